// Round 1
// baseline (1502.771 us; speedup 1.0000x reference)
//
#include <hip/hip_runtime.h>
#include <hip/hip_bf16.h>

#define TT 4
#define HHEADS 4
#define DD 128
#define HD 512   // H * D_OUT

__device__ __forceinline__ float lrelu(float z) { return z > 0.f ? z : 0.2f * z; }
__device__ __forceinline__ float bf2f(unsigned short u) {
  union { unsigned int i; float f; } v; v.i = ((unsigned int)u) << 16; return v.f;
}

// ---------------- GEMM: h[n, 0:512] = x[n, 0:128] @ Wg[0:128, 0:512] (bf16 out)
__global__ __launch_bounds__(256) void gemm_h_kernel(
    const float* __restrict__ x, const float* __restrict__ Wg,
    __hip_bfloat16* __restrict__ h, int N) {
  __shared__ float As[32][65];   // [k][m], padded
  __shared__ float Bs[32][64];   // [k][n]
  const int m0 = blockIdx.x * 64;
  const int c0 = blockIdx.y * 64;
  const int tid = threadIdx.x;
  const int tr = (tid >> 4) << 2;   // 0,4,...,60
  const int tc = (tid & 15) << 2;   // 0,4,...,60
  float acc[4][4] = {};

  for (int k0 = 0; k0 < DD; k0 += 32) {
    // load A tile 64 rows x 32 k  (coalesced in k)
#pragma unroll
    for (int i = 0; i < 8; ++i) {
      int e = tid + i * 256;
      int r = e >> 5, kk = e & 31;
      int n = m0 + r;
      As[kk][r] = (n < N) ? x[(size_t)n * DD + k0 + kk] : 0.f;
    }
    // load B tile 32 k x 64 cols (coalesced in cols)
#pragma unroll
    for (int i = 0; i < 8; ++i) {
      int e = tid + i * 256;
      int kk = e >> 6, c = e & 63;
      Bs[kk][c] = Wg[(size_t)(k0 + kk) * HD + c0 + c];
    }
    __syncthreads();
#pragma unroll
    for (int k = 0; k < 32; ++k) {
      float a[4], b[4];
#pragma unroll
      for (int i = 0; i < 4; ++i) a[i] = As[k][tr + i];
#pragma unroll
      for (int j = 0; j < 4; ++j) b[j] = Bs[k][tc + j];
#pragma unroll
      for (int i = 0; i < 4; ++i)
#pragma unroll
        for (int j = 0; j < 4; ++j) acc[i][j] += a[i] * b[j];
    }
    __syncthreads();
  }
#pragma unroll
  for (int i = 0; i < 4; ++i) {
    int n = m0 + tr + i;
    if (n < N) {
#pragma unroll
      for (int j = 0; j < 4; ++j)
        h[(size_t)n * HD + c0 + tc + j] = __float2bfloat16(acc[i][j]);
    }
  }
}

// ---------------- per-node alpha_s/alpha_d (+ zero denom)
__global__ __launch_bounds__(512) void alpha_kernel(
    const __hip_bfloat16* __restrict__ h, const float* __restrict__ a_s,
    const float* __restrict__ a_d, float* __restrict__ alpha_s,
    float* __restrict__ alpha_d, float* __restrict__ denom, int N) {
  int n = blockIdx.x;
  int d = threadIdx.x;          // 0..511
  int head = d >> 7, w = d & 127;
  float hv = bf2f(((const unsigned short*)h)[(size_t)n * HD + d]);
  float ps = hv * a_s[head * DD + w];
  float pd = hv * a_d[head * DD + w];
  __shared__ float ss[512], sd[512];
  ss[d] = ps; sd[d] = pd;
  __syncthreads();
  for (int off = 64; off >= 1; off >>= 1) {
    if (w < off) { ss[d] += ss[d + off]; sd[d] += sd[d + off]; }
    __syncthreads();
  }
  if (w == 0) {
    alpha_s[n * 4 + head] = ss[d];
    alpha_d[n * 4 + head] = sd[d];
    denom[n * 4 + head] = 0.f;
  }
}

// ---------------- denominator pass (edges of type t + all self loops)
__global__ __launch_bounds__(256) void denom_kernel(
    const int* __restrict__ src, const int* __restrict__ dst,
    const int* __restrict__ attr, int t, const float* __restrict__ as_,
    const float* __restrict__ ad_, float* __restrict__ denom, int E, int N) {
  int i = blockIdx.x * 256 + threadIdx.x;
  if (i >= E + N) return;
  int s, d2;
  if (i < E) {
    if (attr[i] != t) return;
    s = src[i]; d2 = dst[i];
  } else {
    s = d2 = i - E;
  }
  float4 vs = *(const float4*)(as_ + (size_t)s * 4);
  float4 vd = *(const float4*)(ad_ + (size_t)d2 * 4);
  float* dp = denom + (size_t)d2 * 4;
  unsafeAtomicAdd(dp + 0, __expf(lrelu(vs.x + vd.x)));
  unsafeAtomicAdd(dp + 1, __expf(lrelu(vs.y + vd.y)));
  unsafeAtomicAdd(dp + 2, __expf(lrelu(vs.z + vd.z)));
  unsafeAtomicAdd(dp + 3, __expf(lrelu(vs.w + vd.w)));
}

// ---------------- message pass: 1 wave per (edge | self), 2 floats per lane
__global__ __launch_bounds__(256) void msg_kernel(
    const int* __restrict__ src, const int* __restrict__ dst,
    const int* __restrict__ attr, int t, const float* __restrict__ as_,
    const float* __restrict__ ad_, const float* __restrict__ denom,
    const __hip_bfloat16* __restrict__ h, float* __restrict__ acc,
    int E, int N) {
  int item = blockIdx.x * 4 + (threadIdx.x >> 6);
  int lane = threadIdx.x & 63;
  if (item >= E + N) return;
  int s, d2;
  if (item < E) {
    if (attr[item] != t) return;
    s = src[item]; d2 = dst[item];
  } else {
    s = d2 = item - E;
  }
  float4 vs = *(const float4*)(as_ + (size_t)s * 4);
  float4 vd = *(const float4*)(ad_ + (size_t)d2 * 4);
  float4 dn = *(const float4*)(denom + (size_t)d2 * 4);
  float wgt[4];
  wgt[0] = 0.25f * __expf(lrelu(vs.x + vd.x)) / dn.x;
  wgt[1] = 0.25f * __expf(lrelu(vs.y + vd.y)) / dn.y;
  wgt[2] = 0.25f * __expf(lrelu(vs.z + vd.z)) / dn.z;
  wgt[3] = 0.25f * __expf(lrelu(vs.w + vd.w)) / dn.w;
  const unsigned short* hrow = (const unsigned short*)h + (size_t)s * HD;
  int c = lane * 2;
  float a0 = 0.f, a1 = 0.f;
#pragma unroll
  for (int hh = 0; hh < HHEADS; ++hh) {
    ushort2 u = *(const ushort2*)(hrow + hh * DD + c);
    a0 += wgt[hh] * bf2f(u.x);
    a1 += wgt[hh] * bf2f(u.y);
  }
  float* ap = acc + (size_t)d2 * DD + c;
  unsafeAtomicAdd(ap + 0, a0);
  unsafeAtomicAdd(ap + 1, a1);
}

// ---------------- fuse GEMM (50000x512 @ 512x128) + LayerNorm + ReLU
__global__ __launch_bounds__(256) void fuse_kernel(
    const float* __restrict__ acc, const float* __restrict__ b_gat,
    const float* __restrict__ etw, const float* __restrict__ W_fuse,
    const float* __restrict__ b_fuse, const float* __restrict__ gamma,
    const float* __restrict__ beta, float* __restrict__ out, int N) {
  // softmax of edge-type weights (redundant per block; 4 elements)
  float e0 = etw[0], e1 = etw[1], e2 = etw[2], e3 = etw[3];
  float mx = fmaxf(fmaxf(e0, e1), fmaxf(e2, e3));
  float x0 = __expf(e0 - mx), x1 = __expf(e1 - mx), x2 = __expf(e2 - mx),
        x3 = __expf(e3 - mx);
  float inv = 1.f / (x0 + x1 + x2 + x3);
  float w[4] = {x0 * inv, x1 * inv, x2 * inv, x3 * inv};

  __shared__ float As[32][33];    // [k][row]
  __shared__ float Bs[32][128];   // [k][col]
  const int n0 = blockIdx.x * 32;
  const int tid = threadIdx.x;
  const int tr = tid >> 5;        // 0..7
  const int tc = tid & 31;        // 0..31
  float accv[4][4] = {};

  for (int k0 = 0; k0 < HD; k0 += 32) {
    // A tile: 32 rows x 32 k, built on the fly from acc (+b_gat, *w[t])
#pragma unroll
    for (int i = 0; i < 4; ++i) {
      int idx = tid + i * 256;
      int r = idx >> 5, kk = idx & 31;
      int n = n0 + r;
      int k = k0 + kk;
      int t = k >> 7, d = k & 127;
      float v = 0.f;
      if (n < N)
        v = w[t] * (acc[((size_t)t * N + n) * DD + d] + b_gat[t * DD + d]);
      As[kk][r] = v;
    }
    // B tile: 32 k x 128 cols
#pragma unroll
    for (int i = 0; i < 16; ++i) {
      int idx = tid + i * 256;
      int k = idx >> 7, c = idx & 127;
      Bs[k][c] = W_fuse[(size_t)(k0 + k) * DD + c];
    }
    __syncthreads();
#pragma unroll
    for (int k = 0; k < 32; ++k) {
      float a[4], b[4];
#pragma unroll
      for (int i = 0; i < 4; ++i) a[i] = As[k][tr * 4 + i];
#pragma unroll
      for (int j = 0; j < 4; ++j) b[j] = Bs[k][tc * 4 + j];
#pragma unroll
      for (int i = 0; i < 4; ++i)
#pragma unroll
        for (int j = 0; j < 4; ++j) accv[i][j] += a[i] * b[j];
    }
    __syncthreads();
  }

  // epilogue: +b_fuse, LayerNorm over 128 cols per row, ReLU
  float bf[4], gm[4], bt[4];
#pragma unroll
  for (int j = 0; j < 4; ++j) {
    bf[j] = b_fuse[tc * 4 + j];
    gm[j] = gamma[tc * 4 + j];
    bt[j] = beta[tc * 4 + j];
  }
#pragma unroll
  for (int i = 0; i < 4; ++i) {
    float y[4];
    float s = 0.f, ss = 0.f;
#pragma unroll
    for (int j = 0; j < 4; ++j) {
      y[j] = accv[i][j] + bf[j];
      s += y[j];
      ss += y[j] * y[j];
    }
    // reduce over the 32 threads (tc) sharing this row; they are one 32-lane half
#pragma unroll
    for (int off = 16; off >= 1; off >>= 1) {
      s += __shfl_xor(s, off, 64);
      ss += __shfl_xor(ss, off, 64);
    }
    float mean = s * (1.f / 128.f);
    float var = ss * (1.f / 128.f) - mean * mean;
    float rstd = rsqrtf(var + 1e-5f);
    int n = n0 + tr * 4 + i;
    if (n < N) {
      float4 o;
      float* op = (float*)&o;
#pragma unroll
      for (int j = 0; j < 4; ++j) {
        float v = (y[j] - mean) * rstd * gm[j] + bt[j];
        op[j] = v > 0.f ? v : 0.f;
      }
      *(float4*)(out + (size_t)n * DD + tc * 4) = o;
    }
  }
}

extern "C" void kernel_launch(void* const* d_in, const int* in_sizes, int n_in,
                              void* d_out, int out_size, void* d_ws, size_t ws_size,
                              hipStream_t stream) {
  const float* x      = (const float*)d_in[0];
  const int*   ei     = (const int*)d_in[1];
  const int*   attr   = (const int*)d_in[2];
  const float* Wg     = (const float*)d_in[3];
  const float* a_src  = (const float*)d_in[4];
  const float* a_dst  = (const float*)d_in[5];
  const float* b_gat  = (const float*)d_in[6];
  const float* etw    = (const float*)d_in[7];
  const float* W_fuse = (const float*)d_in[8];
  const float* b_fuse = (const float*)d_in[9];
  const float* gamma  = (const float*)d_in[10];
  const float* beta   = (const float*)d_in[11];

  const int N = in_sizes[0] / DD;
  const int E = in_sizes[2];
  const int* src = ei;
  const int* dst = ei + E;

  char* ws = (char*)d_ws;
  size_t off = 0;
  auto alloc = [&](size_t bytes) {
    void* p = ws + off;
    off += (bytes + 255) & ~(size_t)255;
    return p;
  };
  float* acc             = (float*)alloc((size_t)TT * N * DD * sizeof(float));
  __hip_bfloat16* h      = (__hip_bfloat16*)alloc((size_t)N * HD * sizeof(__hip_bfloat16));
  float* as_             = (float*)alloc((size_t)N * 4 * sizeof(float));
  float* ad_             = (float*)alloc((size_t)N * 4 * sizeof(float));
  float* denom           = (float*)alloc((size_t)N * 4 * sizeof(float));

  hipMemsetAsync(acc, 0, (size_t)TT * N * DD * sizeof(float), stream);

  dim3 ggrid((N + 63) / 64, HD / 64);
  int items = E + N;
  for (int t = 0; t < TT; ++t) {
    gemm_h_kernel<<<ggrid, 256, 0, stream>>>(x, Wg + (size_t)t * DD * HD, h, N);
    alpha_kernel<<<N, 512, 0, stream>>>(h, a_src + t * HHEADS * DD,
                                        a_dst + t * HHEADS * DD, as_, ad_, denom, N);
    denom_kernel<<<(items + 255) / 256, 256, 0, stream>>>(src, dst, attr, t, as_,
                                                          ad_, denom, E, N);
    msg_kernel<<<(items + 3) / 4, 256, 0, stream>>>(
        src, dst, attr, t, as_, ad_, denom, h, acc + (size_t)t * N * DD, E, N);
  }
  fuse_kernel<<<(N + 31) / 32, 256, 0, stream>>>(acc, b_gat, etw, W_fuse, b_fuse,
                                                 gamma, beta, (float*)d_out, N);
}

// Round 3
// 843.059 us; speedup vs baseline: 1.7825x; 1.7825x over previous
//
#include <hip/hip_runtime.h>
#include <hip/hip_bf16.h>

#define TT 4
#define HH 4
#define DD 128
#define HD 512   // H * D_OUT

typedef __attribute__((ext_vector_type(8))) short short8;
typedef __attribute__((ext_vector_type(4))) float f32x4;

__device__ __forceinline__ float lrelu(float z) { return z > 0.f ? z : 0.2f * z; }
__device__ __forceinline__ float bf2f(unsigned short u) {
  union { unsigned int i; float f; } v; v.i = ((unsigned int)u) << 16; return v.f;
}
__device__ __forceinline__ unsigned short f2b(float f) {
  union { float f; unsigned int i; } u; u.f = f;
  unsigned int r = u.i + 0x7fff + ((u.i >> 16) & 1);
  return (unsigned short)(r >> 16);
}

// -------- x (f32) -> xb (bf16)
__global__ __launch_bounds__(256) void convx_kernel(
    const float* __restrict__ x, unsigned short* __restrict__ xb, int total4) {
  int i = blockIdx.x * 256 + threadIdx.x;
  if (i >= total4) return;
  float4 v = ((const float4*)x)[i];
  ushort4 o;
  o.x = f2b(v.x); o.y = f2b(v.y); o.z = f2b(v.z); o.w = f2b(v.w);
  ((ushort4*)xb)[i] = o;
}

// -------- weights prep: WbT [t][c512][k128] bf16 ; P [t][8][128] f32 ; WfT [c128][k512] bf16
__global__ __launch_bounds__(256) void prepw_kernel(
    const float* __restrict__ Wg, const float* __restrict__ a_s,
    const float* __restrict__ a_d, const float* __restrict__ W_fuse,
    unsigned short* __restrict__ WbT, float* __restrict__ P,
    unsigned short* __restrict__ WfT) {
  int bid = blockIdx.x;
  if (bid < 1024) {                     // WbT: 4*512*128 = 262144 elems
    int idx = bid * 256 + threadIdx.x;
    int k = idx & 127, c = (idx >> 7) & 511, t = idx >> 16;
    WbT[idx] = f2b(Wg[(size_t)t * 65536 + k * 512 + c]);
  } else if (bid < 1040) {              // P: 4*8*128 = 4096
    int idx = (bid - 1024) * 256 + threadIdx.x;
    int k = idx & 127, o = (idx >> 7) & 7, t = idx >> 10;
    int head = o & 3;
    const float* av = ((o < 4) ? a_s : a_d) + (t * 4 + head) * 128;
    const float* wrow = Wg + (size_t)t * 65536 + k * 512 + head * 128;
    float s = 0.f;
    for (int d = 0; d < 128; ++d) s += wrow[d] * av[d];
    P[idx] = s;
  } else {                              // WfT: 128*512 = 65536
    int idx = (bid - 1040) * 256 + threadIdx.x;
    int k = idx & 511, c = idx >> 9;
    WfT[idx] = f2b(W_fuse[(size_t)k * 128 + c]);
  }
}

// -------- all-type alpha_s/alpha_d from x @ P ; zero denom
__global__ __launch_bounds__(256) void alpha_all_kernel(
    const float* __restrict__ x, const float* __restrict__ P,
    float* __restrict__ as_, float* __restrict__ ad_,
    float* __restrict__ denom, int N) {
  int n = blockIdx.x * 4 + (threadIdx.x >> 6);
  int l = threadIdx.x & 63;
  if (n >= N) return;
  float x0 = x[(size_t)n * DD + l];
  float x1 = x[(size_t)n * DD + 64 + l];
  float keep = 0.f;
#pragma unroll
  for (int o = 0; o < 32; ++o) {        // o = t*8 + j
    const float* p = P + o * 128;
    float s = x0 * p[l] + x1 * p[64 + l];
    s += __shfl_xor(s, 1);
    s += __shfl_xor(s, 2);
    s += __shfl_xor(s, 4);
    s += __shfl_xor(s, 8);
    s += __shfl_xor(s, 16);
    s += __shfl_xor(s, 32);
    if (l == o) keep = s;
  }
  if (l < 32) {
    int t = l >> 3, j = l & 7;
    if (j < 4) as_[((size_t)t * N + n) * 4 + j] = keep;
    else       ad_[((size_t)t * N + n) * 4 + (j - 4)] = keep;
  } else if (l < 48) {
    int t = (l - 32) >> 2, j = (l - 32) & 3;
    denom[((size_t)t * N + n) * 4 + j] = 0.f;
  }
}

// -------- denominators, all types in one pass
__global__ __launch_bounds__(256) void denom_all_kernel(
    const int* __restrict__ src, const int* __restrict__ dst,
    const int* __restrict__ attr, const float* __restrict__ as_,
    const float* __restrict__ ad_, float* __restrict__ denom, int E, int N) {
  int i = blockIdx.x * 256 + threadIdx.x;
  if (i < E) {
    int t = attr[i];
    float4 va = *(const float4*)(as_ + ((size_t)t * N + src[i]) * 4);
    float4 vb = *(const float4*)(ad_ + ((size_t)t * N + dst[i]) * 4);
    float* dp = denom + ((size_t)t * N + dst[i]) * 4;
    unsafeAtomicAdd(dp + 0, __expf(lrelu(va.x + vb.x)));
    unsafeAtomicAdd(dp + 1, __expf(lrelu(va.y + vb.y)));
    unsafeAtomicAdd(dp + 2, __expf(lrelu(va.z + vb.z)));
    unsafeAtomicAdd(dp + 3, __expf(lrelu(va.w + vb.w)));
  } else if (i < E + N) {
    int n = i - E;
#pragma unroll
    for (int t = 0; t < TT; ++t) {
      float4 va = *(const float4*)(as_ + ((size_t)t * N + n) * 4);
      float4 vb = *(const float4*)(ad_ + ((size_t)t * N + n) * 4);
      float* dp = denom + ((size_t)t * N + n) * 4;
      unsafeAtomicAdd(dp + 0, __expf(lrelu(va.x + vb.x)));
      unsafeAtomicAdd(dp + 1, __expf(lrelu(va.y + vb.y)));
      unsafeAtomicAdd(dp + 2, __expf(lrelu(va.z + vb.z)));
      unsafeAtomicAdd(dp + 3, __expf(lrelu(va.w + vb.w)));
    }
  }
}

// -------- MFMA GEMM: h[N][512] = xb[N][128] @ W   (one edge type)
__global__ __launch_bounds__(256) void mfma_h_kernel(
    const unsigned short* __restrict__ xb, const unsigned short* __restrict__ WbT,
    unsigned short* __restrict__ h, int N) {
  __shared__ uint4 ldsv[2048];  // 32 KB
  unsigned char* lds = (unsigned char*)ldsv;
  const int n0 = blockIdx.x * 128;
  const int c0 = blockIdx.y * 128;
  const int tid = threadIdx.x;
  const int lane = tid & 63;
  const int wid = tid >> 6;
  const int wr = (wid >> 1) * 64, wc = (wid & 1) * 64;
  const int lr = lane & 15, lg = lane >> 4;

  // stage A tile 128x128 bf16, XOR-swizzled
#pragma unroll
  for (int i = 0; i < 8; ++i) {
    int chunk = tid + i * 256;
    int row = chunk >> 4, k16 = chunk & 15;
    int gr = n0 + row;
    uint4 v = make_uint4(0, 0, 0, 0);
    if (gr < N) v = *(const uint4*)(xb + (size_t)gr * DD + k16 * 8);
    *(uint4*)(lds + ((row * 256 + k16 * 16) ^ ((row & 7) << 4))) = v;
  }
  __syncthreads();

  f32x4 acc[4][4] = {};
#pragma unroll
  for (int kk = 0; kk < 4; ++kk) {
    short8 a[4], b[4];
#pragma unroll
    for (int m = 0; m < 4; ++m) {
      int row = wr + m * 16 + lr;
      a[m] = *(const short8*)(lds + ((row * 256 + kk * 64 + (lg << 4)) ^ ((row & 7) << 4)));
    }
#pragma unroll
    for (int n = 0; n < 4; ++n) {
      int col = c0 + wc + n * 16 + lr;
      b[n] = *(const short8*)(WbT + (size_t)col * DD + kk * 32 + (lg << 3));
    }
#pragma unroll
    for (int m = 0; m < 4; ++m)
#pragma unroll
      for (int n = 0; n < 4; ++n)
        acc[m][n] = __builtin_amdgcn_mfma_f32_16x16x32_bf16(a[m], b[n], acc[m][n], 0, 0, 0);
  }
  __syncthreads();

  // bounce C (bf16) through LDS for coalesced store
#pragma unroll
  for (int m = 0; m < 4; ++m)
#pragma unroll
    for (int n = 0; n < 4; ++n) {
      int col = wc + n * 16 + lr;
#pragma unroll
      for (int r = 0; r < 4; ++r) {
        int row = wr + m * 16 + lg * 4 + r;
        *(unsigned short*)(lds + ((row * 256 + col * 2) ^ ((row & 7) << 4))) = f2b(acc[m][n][r]);
      }
    }
  __syncthreads();
#pragma unroll
  for (int i = 0; i < 8; ++i) {
    int chunk = tid + i * 256;
    int row = chunk >> 4, k16 = chunk & 15;
    int gr = n0 + row;
    if (gr < N)
      *(uint4*)(h + (size_t)gr * HD + c0 + k16 * 8) =
          *(const uint4*)(lds + ((row * 256 + k16 * 16) ^ ((row & 7) << 4)));
  }
}

// -------- message pass: 1 wave per (edge | self); acc layout [n][t*128+d]
__global__ __launch_bounds__(256) void msg_kernel(
    const int* __restrict__ src, const int* __restrict__ dst,
    const int* __restrict__ attr, int t, const float* __restrict__ as_,
    const float* __restrict__ ad_, const float* __restrict__ denom,
    const unsigned short* __restrict__ h, float* __restrict__ acc,
    int E, int N) {
  int item = blockIdx.x * 4 + (threadIdx.x >> 6);
  int lane = threadIdx.x & 63;
  if (item >= E + N) return;
  int s, d2;
  if (item < E) {
    if (attr[item] != t) return;
    s = src[item]; d2 = dst[item];
  } else {
    s = d2 = item - E;
  }
  float4 vs = *(const float4*)(as_ + (size_t)s * 4);
  float4 vd = *(const float4*)(ad_ + (size_t)d2 * 4);
  float4 dn = *(const float4*)(denom + (size_t)d2 * 4);
  float wgt[4];
  wgt[0] = 0.25f * __expf(lrelu(vs.x + vd.x)) / dn.x;
  wgt[1] = 0.25f * __expf(lrelu(vs.y + vd.y)) / dn.y;
  wgt[2] = 0.25f * __expf(lrelu(vs.z + vd.z)) / dn.z;
  wgt[3] = 0.25f * __expf(lrelu(vs.w + vd.w)) / dn.w;
  const unsigned short* hrow = h + (size_t)s * HD;
  int c = lane * 2;
  float a0 = 0.f, a1 = 0.f;
#pragma unroll
  for (int hh = 0; hh < HH; ++hh) {
    ushort2 u = *(const ushort2*)(hrow + hh * DD + c);
    a0 += wgt[hh] * bf2f(u.x);
    a1 += wgt[hh] * bf2f(u.y);
  }
  float* ap = acc + (size_t)d2 * HD + t * DD + c;   // [n][t*128+d]
  unsafeAtomicAdd(ap + 0, a0);
  unsafeAtomicAdd(ap + 1, a1);
}

// -------- acc (f32 [n][512]) -> accb (bf16 [n][512]) with w[t]*(acc + b_gat)
__global__ __launch_bounds__(256) void conv_acc_kernel(
    const float* __restrict__ acc, const float* __restrict__ b_gat,
    const float* __restrict__ etw, unsigned short* __restrict__ accb, int N) {
  int i = blockIdx.x * 256 + threadIdx.x;
  int total4 = TT * N * DD / 4;
  if (i >= total4) return;
  int e = i * 4;
  int t = (e >> 7) & 3;       // col = t*128 + d within [n][512]
  int d = e & 127;
  float e0 = etw[0], e1 = etw[1], e2 = etw[2], e3 = etw[3];
  float mx = fmaxf(fmaxf(e0, e1), fmaxf(e2, e3));
  float w0 = __expf(e0 - mx), w1 = __expf(e1 - mx), w2 = __expf(e2 - mx), w3 = __expf(e3 - mx);
  float inv = 1.f / (w0 + w1 + w2 + w3);
  float wt = ((t == 0) ? w0 : (t == 1) ? w1 : (t == 2) ? w2 : w3) * inv;
  float4 v = ((const float4*)acc)[i];
  float4 bg = *(const float4*)(b_gat + t * DD + d);
  ushort4 o;
  o.x = f2b(wt * (v.x + bg.x));
  o.y = f2b(wt * (v.y + bg.y));
  o.z = f2b(wt * (v.z + bg.z));
  o.w = f2b(wt * (v.w + bg.w));
  ((ushort4*)accb)[i] = o;
}

// -------- MFMA fuse GEMM [N x 512] @ [512 x 128] + LayerNorm + ReLU
__global__ __launch_bounds__(128) void fuse_mfma_kernel(
    const unsigned short* __restrict__ accb, const unsigned short* __restrict__ WfT,
    const float* __restrict__ b_fuse, const float* __restrict__ gamma,
    const float* __restrict__ beta, float* __restrict__ out, int N) {
  __shared__ uint4 ldsv[2048];  // 32 KB (A-stage 16KB, then f32 C-buf 32KB)
  __shared__ float smean[64], srstd[64];
  unsigned char* lds = (unsigned char*)ldsv;
  const int n0 = blockIdx.x * 64;
  const int tid = threadIdx.x;
  const int lane = tid & 63;
  const int wid = tid >> 6;   // 0..1
  const int wc = wid * 64;
  const int lr = lane & 15, lg = lane >> 4;

  f32x4 acc[4][4] = {};
  for (int kt = 0; kt < 4; ++kt) {
    // stage A: 64 rows x 128 k bf16, swizzled
#pragma unroll
    for (int i = 0; i < 8; ++i) {
      int chunk = tid + i * 128;        // 0..1023
      int row = chunk >> 4, k16 = chunk & 15;
      int gr = n0 + row;
      uint4 v = make_uint4(0, 0, 0, 0);
      if (gr < N) v = *(const uint4*)(accb + (size_t)gr * HD + kt * 128 + k16 * 8);
      *(uint4*)(lds + ((row * 256 + k16 * 16) ^ ((row & 7) << 4))) = v;
    }
    __syncthreads();
#pragma unroll
    for (int kk = 0; kk < 4; ++kk) {
      short8 a[4], b[4];
#pragma unroll
      for (int m = 0; m < 4; ++m) {
        int row = m * 16 + lr;
        a[m] = *(const short8*)(lds + ((row * 256 + kk * 64 + (lg << 4)) ^ ((row & 7) << 4)));
      }
#pragma unroll
      for (int n = 0; n < 4; ++n) {
        int col = wc + n * 16 + lr;
        b[n] = *(const short8*)(WfT + (size_t)col * HD + kt * 128 + kk * 32 + (lg << 3));
      }
#pragma unroll
      for (int m = 0; m < 4; ++m)
#pragma unroll
        for (int n = 0; n < 4; ++n)
          acc[m][n] = __builtin_amdgcn_mfma_f32_16x16x32_bf16(a[m], b[n], acc[m][n], 0, 0, 0);
    }
    __syncthreads();
  }

  // bounce f32 C (+b_fuse) into LDS
#pragma unroll
  for (int m = 0; m < 4; ++m)
#pragma unroll
    for (int n = 0; n < 4; ++n) {
      int col = wc + n * 16 + lr;
      float bf = b_fuse[col];
#pragma unroll
      for (int r = 0; r < 4; ++r) {
        int row = m * 16 + lg * 4 + r;
        *(float*)(lds + ((row * 512 + col * 4) ^ ((row & 7) << 4))) = acc[m][n][r] + bf;
      }
    }
  __syncthreads();

  // LN stats: 2 threads per row
  {
    int row = tid >> 1, half = tid & 1;
    float s = 0.f, ss = 0.f;
#pragma unroll
    for (int j = 0; j < 16; ++j) {
      int byte = (row * 512 + half * 256 + j * 16) ^ ((row & 7) << 4);
      float4 v = *(const float4*)(lds + byte);
      s += v.x + v.y + v.z + v.w;
      ss += v.x * v.x + v.y * v.y + v.z * v.z + v.w * v.w;
    }
    s += __shfl_xor(s, 1);
    ss += __shfl_xor(ss, 1);
    if (half == 0) {
      float mean = s * (1.f / 128.f);
      float var = ss * (1.f / 128.f) - mean * mean;
      smean[row] = mean;
      srstd[row] = rsqrtf(var + 1e-5f);
    }
  }
  __syncthreads();

  // apply LN + ReLU, coalesced store
#pragma unroll
  for (int i = 0; i < 16; ++i) {
    int chunk = tid + i * 128;          // 0..2047
    int row = chunk >> 5, c4 = chunk & 31;
    int gr = n0 + row;
    if (gr < N) {
      int byte = (row * 512 + c4 * 16) ^ ((row & 7) << 4);
      float4 v = *(const float4*)(lds + byte);
      float mean = smean[row], rstd = srstd[row];
      float4 g = *(const float4*)(gamma + c4 * 4);
      float4 bb = *(const float4*)(beta + c4 * 4);
      float4 o;
      o.x = fmaxf(0.f, (v.x - mean) * rstd * g.x + bb.x);
      o.y = fmaxf(0.f, (v.y - mean) * rstd * g.y + bb.y);
      o.z = fmaxf(0.f, (v.z - mean) * rstd * g.z + bb.z);
      o.w = fmaxf(0.f, (v.w - mean) * rstd * g.w + bb.w);
      *(float4*)(out + (size_t)gr * DD + c4 * 4) = o;
    }
  }
}

extern "C" void kernel_launch(void* const* d_in, const int* in_sizes, int n_in,
                              void* d_out, int out_size, void* d_ws, size_t ws_size,
                              hipStream_t stream) {
  const float* x      = (const float*)d_in[0];
  const int*   ei     = (const int*)d_in[1];
  const int*   attr   = (const int*)d_in[2];
  const float* Wg     = (const float*)d_in[3];
  const float* a_src  = (const float*)d_in[4];
  const float* a_dst  = (const float*)d_in[5];
  const float* b_gat  = (const float*)d_in[6];
  const float* etw    = (const float*)d_in[7];
  const float* W_fuse = (const float*)d_in[8];
  const float* b_fuse = (const float*)d_in[9];
  const float* gamma  = (const float*)d_in[10];
  const float* beta   = (const float*)d_in[11];

  const int N = in_sizes[0] / DD;
  const int E = in_sizes[2];
  const int* src = ei;
  const int* dst = ei + E;

  char* ws = (char*)d_ws;
  size_t off = 0;
  auto alloc = [&](size_t bytes) {
    void* p = ws + off;
    off += (bytes + 255) & ~(size_t)255;
    return p;
  };
  float* acc           = (float*)alloc((size_t)N * HD * sizeof(float));            // 102.4MB [n][512]
  unsigned short* h    = (unsigned short*)alloc((size_t)N * HD * 2);               // 51.2MB (reused as accb)
  unsigned short* xb   = (unsigned short*)alloc((size_t)N * DD * 2);               // 12.8MB
  unsigned short* WbT  = (unsigned short*)alloc((size_t)TT * HD * DD * 2);         // 0.5MB
  unsigned short* WfT  = (unsigned short*)alloc((size_t)DD * HD * 2);              // 0.13MB
  float* P             = (float*)alloc((size_t)TT * 8 * DD * sizeof(float));       // 16KB
  float* as_           = (float*)alloc((size_t)TT * N * 4 * sizeof(float));        // 3.2MB
  float* ad_           = (float*)alloc((size_t)TT * N * 4 * sizeof(float));
  float* denom         = (float*)alloc((size_t)TT * N * 4 * sizeof(float));

  hipMemsetAsync(acc, 0, (size_t)N * HD * sizeof(float), stream);

  int total4x = N * DD / 4;
  convx_kernel<<<(total4x + 255) / 256, 256, 0, stream>>>(x, xb, total4x);
  prepw_kernel<<<1296, 256, 0, stream>>>(Wg, a_src, a_dst, W_fuse, WbT, P, WfT);
  alpha_all_kernel<<<(N + 3) / 4, 256, 0, stream>>>(x, P, as_, ad_, denom, N);

  int items = E + N;
  denom_all_kernel<<<(items + 255) / 256, 256, 0, stream>>>(src, dst, attr, as_, ad_, denom, E, N);

  dim3 hgrid((N + 127) / 128, 4);
  for (int t = 0; t < TT; ++t) {
    mfma_h_kernel<<<hgrid, 256, 0, stream>>>(xb, WbT + (size_t)t * HD * DD, h, N);
    msg_kernel<<<(items + 3) / 4, 256, 0, stream>>>(
        src, dst, attr, t, as_ + (size_t)t * N * 4, ad_ + (size_t)t * N * 4,
        denom + (size_t)t * N * 4, h, acc, E, N);
  }

  unsigned short* accb = h;  // h is dead after the last msg pass
  int total4a = TT * N * DD / 4;
  conv_acc_kernel<<<(total4a + 255) / 256, 256, 0, stream>>>(acc, b_gat, etw, accb, N);
  fuse_mfma_kernel<<<(N + 63) / 64, 128, 0, stream>>>(accb, WfT, b_fuse, gamma, beta,
                                                      (float*)d_out, N);
}

// Round 4
// 476.707 us; speedup vs baseline: 3.1524x; 1.7685x over previous
//
#include <hip/hip_runtime.h>
#include <hip/hip_bf16.h>

#define TT 4
#define HH 4
#define DD 128
#define HD 512   // H * D_OUT

typedef __attribute__((ext_vector_type(8))) short short8;
typedef __attribute__((ext_vector_type(4))) float f32x4;

__device__ __forceinline__ float lrelu(float z) { return z > 0.f ? z : 0.2f * z; }
__device__ __forceinline__ float bf2f(unsigned short u) {
  union { unsigned int i; float f; } v; v.i = ((unsigned int)u) << 16; return v.f;
}
__device__ __forceinline__ unsigned short f2b(float f) {
  union { float f; unsigned int i; } u; u.f = f;
  unsigned int r = u.i + 0x7fff + ((u.i >> 16) & 1);
  return (unsigned short)(r >> 16);
}

// -------- x (f32) -> xb (bf16)
__global__ __launch_bounds__(256) void convx_kernel(
    const float* __restrict__ x, unsigned short* __restrict__ xb, int total4) {
  int i = blockIdx.x * 256 + threadIdx.x;
  if (i >= total4) return;
  float4 v = ((const float4*)x)[i];
  ushort4 o;
  o.x = f2b(v.x); o.y = f2b(v.y); o.z = f2b(v.z); o.w = f2b(v.w);
  ((ushort4*)xb)[i] = o;
}

// -------- weights prep: WbT [t][c512][k128] bf16 ; P [t][8][128] f32 ; WfT [c128][k512] bf16
__global__ __launch_bounds__(256) void prepw_kernel(
    const float* __restrict__ Wg, const float* __restrict__ a_s,
    const float* __restrict__ a_d, const float* __restrict__ W_fuse,
    unsigned short* __restrict__ WbT, float* __restrict__ P,
    unsigned short* __restrict__ WfT) {
  int bid = blockIdx.x;
  if (bid < 1024) {                     // WbT: 4*512*128 = 262144 elems
    int idx = bid * 256 + threadIdx.x;
    int k = idx & 127, c = (idx >> 7) & 511, t = idx >> 16;
    WbT[idx] = f2b(Wg[(size_t)t * 65536 + k * 512 + c]);
  } else if (bid < 1040) {              // P: 4*8*128 = 4096
    int idx = (bid - 1024) * 256 + threadIdx.x;
    int k = idx & 127, o = (idx >> 7) & 7, t = idx >> 10;
    int head = o & 3;
    const float* av = ((o < 4) ? a_s : a_d) + (t * 4 + head) * 128;
    const float* wrow = Wg + (size_t)t * 65536 + k * 512 + head * 128;
    float s = 0.f;
    for (int d = 0; d < 128; ++d) s += wrow[d] * av[d];
    P[idx] = s;
  } else {                              // WfT: 128*512 = 65536
    int idx = (bid - 1040) * 256 + threadIdx.x;
    int k = idx & 511, c = idx >> 9;
    WfT[idx] = f2b(W_fuse[(size_t)k * 128 + c]);
  }
}

// -------- all-type alpha_s/alpha_d from x @ P
__global__ __launch_bounds__(256) void alpha_all_kernel(
    const float* __restrict__ x, const float* __restrict__ P,
    float* __restrict__ as_, float* __restrict__ ad_, int N) {
  int n = blockIdx.x * 4 + (threadIdx.x >> 6);
  int l = threadIdx.x & 63;
  if (n >= N) return;
  float x0 = x[(size_t)n * DD + l];
  float x1 = x[(size_t)n * DD + 64 + l];
  float keep = 0.f;
#pragma unroll
  for (int o = 0; o < 32; ++o) {        // o = t*8 + j
    const float* p = P + o * 128;
    float s = x0 * p[l] + x1 * p[64 + l];
    s += __shfl_xor(s, 1);
    s += __shfl_xor(s, 2);
    s += __shfl_xor(s, 4);
    s += __shfl_xor(s, 8);
    s += __shfl_xor(s, 16);
    s += __shfl_xor(s, 32);
    if (l == o) keep = s;
  }
  if (l < 32) {
    int t = l >> 3, j = l & 7;
    if (j < 4) as_[((size_t)t * N + n) * 4 + j] = keep;
    else       ad_[((size_t)t * N + n) * 4 + (j - 4)] = keep;
  }
}

// -------- counting sort of edges by (type, dst) --------
__global__ __launch_bounds__(256) void hist_kernel(
    const int* __restrict__ dst, const int* __restrict__ attr,
    int* __restrict__ deg, int E, int N) {
  int e = blockIdx.x * 256 + threadIdx.x;
  if (e < E) atomicAdd(&deg[attr[e] * N + dst[e]], 1);
}

__global__ __launch_bounds__(1024) void scan1_kernel(
    const int* __restrict__ deg, int* __restrict__ rowptr,
    int* __restrict__ sums, int M) {
  __shared__ int sh[1024];
  int i = blockIdx.x * 1024 + threadIdx.x;
  int v = (i < M) ? deg[i] : 0;
  sh[threadIdx.x] = v;
  __syncthreads();
  for (int off = 1; off < 1024; off <<= 1) {
    int x = (threadIdx.x >= off) ? sh[threadIdx.x - off] : 0;
    __syncthreads();
    sh[threadIdx.x] += x;
    __syncthreads();
  }
  if (i < M) rowptr[i] = sh[threadIdx.x] - v;   // exclusive within chunk
  if (threadIdx.x == 1023) sums[blockIdx.x] = sh[1023];
}

__global__ __launch_bounds__(256) void scan2_kernel(int* __restrict__ sums, int nch) {
  __shared__ int sh[256];
  int v = (threadIdx.x < nch) ? sums[threadIdx.x] : 0;
  sh[threadIdx.x] = v;
  __syncthreads();
  for (int off = 1; off < 256; off <<= 1) {
    int x = (threadIdx.x >= off) ? sh[threadIdx.x - off] : 0;
    __syncthreads();
    sh[threadIdx.x] += x;
    __syncthreads();
  }
  if (threadIdx.x < nch) sums[threadIdx.x] = sh[threadIdx.x] - v;  // exclusive
}

__global__ __launch_bounds__(1024) void scan3_kernel(
    int* __restrict__ rowptr, const int* __restrict__ sums,
    int* __restrict__ cursor, int M) {
  int i = blockIdx.x * 1024 + threadIdx.x;
  if (i < M) {
    int r = rowptr[i] + sums[blockIdx.x];
    rowptr[i] = r;
    cursor[i] = r;
  }
}

__global__ __launch_bounds__(256) void scatter_kernel(
    const int* __restrict__ src, const int* __restrict__ dst,
    const int* __restrict__ attr, int* __restrict__ cursor,
    int* __restrict__ slist, int E, int N) {
  int e = blockIdx.x * 256 + threadIdx.x;
  if (e >= E) return;
  int p = atomicAdd(&cursor[attr[e] * N + dst[e]], 1);
  slist[p] = src[e];
}

// -------- MFMA GEMM: h[N][512] = xb[N][128] @ W   (one edge type)
__global__ __launch_bounds__(256) void mfma_h_kernel(
    const unsigned short* __restrict__ xb, const unsigned short* __restrict__ WbT,
    unsigned short* __restrict__ h, int N) {
  __shared__ uint4 ldsv[2048];  // 32 KB
  unsigned char* lds = (unsigned char*)ldsv;
  const int n0 = blockIdx.x * 128;
  const int c0 = blockIdx.y * 128;
  const int tid = threadIdx.x;
  const int lane = tid & 63;
  const int wid = tid >> 6;
  const int wr = (wid >> 1) * 64, wc = (wid & 1) * 64;
  const int lr = lane & 15, lg = lane >> 4;

#pragma unroll
  for (int i = 0; i < 8; ++i) {
    int chunk = tid + i * 256;
    int row = chunk >> 4, k16 = chunk & 15;
    int gr = n0 + row;
    uint4 v = make_uint4(0, 0, 0, 0);
    if (gr < N) v = *(const uint4*)(xb + (size_t)gr * DD + k16 * 8);
    *(uint4*)(lds + ((row * 256 + k16 * 16) ^ ((row & 7) << 4))) = v;
  }
  __syncthreads();

  f32x4 acc[4][4] = {};
#pragma unroll
  for (int kk = 0; kk < 4; ++kk) {
    short8 a[4], b[4];
#pragma unroll
    for (int m = 0; m < 4; ++m) {
      int row = wr + m * 16 + lr;
      a[m] = *(const short8*)(lds + ((row * 256 + kk * 64 + (lg << 4)) ^ ((row & 7) << 4)));
    }
#pragma unroll
    for (int n = 0; n < 4; ++n) {
      int col = c0 + wc + n * 16 + lr;
      b[n] = *(const short8*)(WbT + (size_t)col * DD + kk * 32 + (lg << 3));
    }
#pragma unroll
    for (int m = 0; m < 4; ++m)
#pragma unroll
      for (int n = 0; n < 4; ++n)
        acc[m][n] = __builtin_amdgcn_mfma_f32_16x16x32_bf16(a[m], b[n], acc[m][n], 0, 0, 0);
  }
  __syncthreads();

#pragma unroll
  for (int m = 0; m < 4; ++m)
#pragma unroll
    for (int n = 0; n < 4; ++n) {
      int col = wc + n * 16 + lr;
#pragma unroll
      for (int r = 0; r < 4; ++r) {
        int row = wr + m * 16 + lg * 4 + r;
        *(unsigned short*)(lds + ((row * 256 + col * 2) ^ ((row & 7) << 4))) = f2b(acc[m][n][r]);
      }
    }
  __syncthreads();
#pragma unroll
  for (int i = 0; i < 8; ++i) {
    int chunk = tid + i * 256;
    int row = chunk >> 4, k16 = chunk & 15;
    int gr = n0 + row;
    if (gr < N)
      *(uint4*)(h + (size_t)gr * HD + c0 + k16 * 8) =
          *(const uint4*)(lds + ((row * 256 + k16 * 16) ^ ((row & 7) << 4)));
  }
}

// -------- gather message pass: one wave per dst node; no atomics.
// Writes bf16 w[t]*(head_mean + b_gat) directly into accb[d][t*128+c].
__global__ __launch_bounds__(256) void msg_gather_kernel(
    const int* __restrict__ slist, const int* __restrict__ rowptr,
    const int* __restrict__ deg, const float* __restrict__ as_,
    const float* __restrict__ ad_, const unsigned short* __restrict__ h,
    const float* __restrict__ b_gat, const float* __restrict__ etw,
    unsigned short* __restrict__ accb, int t, int N) {
  int d = blockIdx.x * 4 + (threadIdx.x >> 6);
  if (d >= N) return;
  int lane = threadIdx.x & 63;
  size_t tn = (size_t)t * N;

  float4 ad4 = *(const float4*)(ad_ + (tn + d) * 4);
  float4 av  = *(const float4*)(as_ + (tn + d) * 4);
  float num0 = __expf(lrelu(av.x + ad4.x));
  float num1 = __expf(lrelu(av.y + ad4.y));
  float num2 = __expf(lrelu(av.z + ad4.z));
  float num3 = __expf(lrelu(av.w + ad4.w));
  float den0 = num0, den1 = num1, den2 = num2, den3 = num3;

  int base = rowptr[tn + d], dg = deg[tn + d];
  for (int i = 0; i < dg; ++i) {
    int s = slist[base + i];
    float4 a = *(const float4*)(as_ + (tn + s) * 4);
    den0 += __expf(lrelu(a.x + ad4.x));
    den1 += __expf(lrelu(a.y + ad4.y));
    den2 += __expf(lrelu(a.z + ad4.z));
    den3 += __expf(lrelu(a.w + ad4.w));
  }
  float r0 = 1.f / den0, r1 = 1.f / den1, r2 = 1.f / den2, r3 = 1.f / den3;

  int c = lane * 2;
  float a0, a1;
  {  // self-loop message
    const unsigned short* hr = h + (size_t)d * HD;
    ushort2 u0 = *(const ushort2*)(hr + 0 * DD + c);
    ushort2 u1 = *(const ushort2*)(hr + 1 * DD + c);
    ushort2 u2 = *(const ushort2*)(hr + 2 * DD + c);
    ushort2 u3 = *(const ushort2*)(hr + 3 * DD + c);
    float w0 = num0 * r0, w1 = num1 * r1, w2 = num2 * r2, w3 = num3 * r3;
    a0 = w0 * bf2f(u0.x) + w1 * bf2f(u1.x) + w2 * bf2f(u2.x) + w3 * bf2f(u3.x);
    a1 = w0 * bf2f(u0.y) + w1 * bf2f(u1.y) + w2 * bf2f(u2.y) + w3 * bf2f(u3.y);
  }
  for (int i = 0; i < dg; ++i) {
    int s = slist[base + i];
    float4 a = *(const float4*)(as_ + (tn + s) * 4);
    float w0 = __expf(lrelu(a.x + ad4.x)) * r0;
    float w1 = __expf(lrelu(a.y + ad4.y)) * r1;
    float w2 = __expf(lrelu(a.z + ad4.z)) * r2;
    float w3 = __expf(lrelu(a.w + ad4.w)) * r3;
    const unsigned short* hr = h + (size_t)s * HD;
    ushort2 u0 = *(const ushort2*)(hr + 0 * DD + c);
    ushort2 u1 = *(const ushort2*)(hr + 1 * DD + c);
    ushort2 u2 = *(const ushort2*)(hr + 2 * DD + c);
    ushort2 u3 = *(const ushort2*)(hr + 3 * DD + c);
    a0 += w0 * bf2f(u0.x) + w1 * bf2f(u1.x) + w2 * bf2f(u2.x) + w3 * bf2f(u3.x);
    a1 += w0 * bf2f(u0.y) + w1 * bf2f(u1.y) + w2 * bf2f(u2.y) + w3 * bf2f(u3.y);
  }

  // edge-type softmax weight
  float e0 = etw[0], e1 = etw[1], e2 = etw[2], e3 = etw[3];
  float mx = fmaxf(fmaxf(e0, e1), fmaxf(e2, e3));
  float x0 = __expf(e0 - mx), x1 = __expf(e1 - mx), x2 = __expf(e2 - mx), x3 = __expf(e3 - mx);
  float wt = ((t == 0) ? x0 : (t == 1) ? x1 : (t == 2) ? x2 : x3) / (x0 + x1 + x2 + x3);

  float2 bg = *(const float2*)(b_gat + t * DD + c);
  ushort2 o;
  o.x = f2b(wt * (0.25f * a0 + bg.x));
  o.y = f2b(wt * (0.25f * a1 + bg.y));
  *(ushort2*)(accb + (size_t)d * HD + t * DD + c) = o;
}

// -------- MFMA fuse GEMM [N x 512] @ [512 x 128] + LayerNorm + ReLU
__global__ __launch_bounds__(128) void fuse_mfma_kernel(
    const unsigned short* __restrict__ accb, const unsigned short* __restrict__ WfT,
    const float* __restrict__ b_fuse, const float* __restrict__ gamma,
    const float* __restrict__ beta, float* __restrict__ out, int N) {
  __shared__ uint4 ldsv[2048];  // 32 KB (A-stage 16KB, then f32 C-buf 32KB)
  __shared__ float smean[64], srstd[64];
  unsigned char* lds = (unsigned char*)ldsv;
  const int n0 = blockIdx.x * 64;
  const int tid = threadIdx.x;
  const int lane = tid & 63;
  const int wid = tid >> 6;   // 0..1
  const int wc = wid * 64;
  const int lr = lane & 15, lg = lane >> 4;

  f32x4 acc[4][4] = {};
  for (int kt = 0; kt < 4; ++kt) {
#pragma unroll
    for (int i = 0; i < 8; ++i) {
      int chunk = tid + i * 128;        // 0..1023
      int row = chunk >> 4, k16 = chunk & 15;
      int gr = n0 + row;
      uint4 v = make_uint4(0, 0, 0, 0);
      if (gr < N) v = *(const uint4*)(accb + (size_t)gr * HD + kt * 128 + k16 * 8);
      *(uint4*)(lds + ((row * 256 + k16 * 16) ^ ((row & 7) << 4))) = v;
    }
    __syncthreads();
#pragma unroll
    for (int kk = 0; kk < 4; ++kk) {
      short8 a[4], b[4];
#pragma unroll
      for (int m = 0; m < 4; ++m) {
        int row = m * 16 + lr;
        a[m] = *(const short8*)(lds + ((row * 256 + kk * 64 + (lg << 4)) ^ ((row & 7) << 4)));
      }
#pragma unroll
      for (int n = 0; n < 4; ++n) {
        int col = wc + n * 16 + lr;
        b[n] = *(const short8*)(WfT + (size_t)col * HD + kt * 128 + kk * 32 + (lg << 3));
      }
#pragma unroll
      for (int m = 0; m < 4; ++m)
#pragma unroll
        for (int n = 0; n < 4; ++n)
          acc[m][n] = __builtin_amdgcn_mfma_f32_16x16x32_bf16(a[m], b[n], acc[m][n], 0, 0, 0);
    }
    __syncthreads();
  }

#pragma unroll
  for (int m = 0; m < 4; ++m)
#pragma unroll
    for (int n = 0; n < 4; ++n) {
      int col = wc + n * 16 + lr;
      float bf = b_fuse[col];
#pragma unroll
      for (int r = 0; r < 4; ++r) {
        int row = m * 16 + lg * 4 + r;
        *(float*)(lds + ((row * 512 + col * 4) ^ ((row & 7) << 4))) = acc[m][n][r] + bf;
      }
    }
  __syncthreads();

  {
    int row = tid >> 1, half = tid & 1;
    float s = 0.f, ss = 0.f;
#pragma unroll
    for (int j = 0; j < 16; ++j) {
      int byte = (row * 512 + half * 256 + j * 16) ^ ((row & 7) << 4);
      float4 v = *(const float4*)(lds + byte);
      s += v.x + v.y + v.z + v.w;
      ss += v.x * v.x + v.y * v.y + v.z * v.z + v.w * v.w;
    }
    s += __shfl_xor(s, 1);
    ss += __shfl_xor(ss, 1);
    if (half == 0) {
      float mean = s * (1.f / 128.f);
      float var = ss * (1.f / 128.f) - mean * mean;
      smean[row] = mean;
      srstd[row] = rsqrtf(var + 1e-5f);
    }
  }
  __syncthreads();

#pragma unroll
  for (int i = 0; i < 16; ++i) {
    int chunk = tid + i * 128;          // 0..2047
    int row = chunk >> 5, c4 = chunk & 31;
    int gr = n0 + row;
    if (gr < N) {
      int byte = (row * 512 + c4 * 16) ^ ((row & 7) << 4);
      float4 v = *(const float4*)(lds + byte);
      float mean = smean[row], rstd = srstd[row];
      float4 g = *(const float4*)(gamma + c4 * 4);
      float4 bb = *(const float4*)(beta + c4 * 4);
      float4 o;
      o.x = fmaxf(0.f, (v.x - mean) * rstd * g.x + bb.x);
      o.y = fmaxf(0.f, (v.y - mean) * rstd * g.y + bb.y);
      o.z = fmaxf(0.f, (v.z - mean) * rstd * g.z + bb.z);
      o.w = fmaxf(0.f, (v.w - mean) * rstd * g.w + bb.w);
      *(float4*)(out + (size_t)gr * DD + c4 * 4) = o;
    }
  }
}

extern "C" void kernel_launch(void* const* d_in, const int* in_sizes, int n_in,
                              void* d_out, int out_size, void* d_ws, size_t ws_size,
                              hipStream_t stream) {
  const float* x      = (const float*)d_in[0];
  const int*   ei     = (const int*)d_in[1];
  const int*   attr   = (const int*)d_in[2];
  const float* Wg     = (const float*)d_in[3];
  const float* a_src  = (const float*)d_in[4];
  const float* a_dst  = (const float*)d_in[5];
  const float* b_gat  = (const float*)d_in[6];
  const float* etw    = (const float*)d_in[7];
  const float* W_fuse = (const float*)d_in[8];
  const float* b_fuse = (const float*)d_in[9];
  const float* gamma  = (const float*)d_in[10];
  const float* beta   = (const float*)d_in[11];

  const int N = in_sizes[0] / DD;
  const int E = in_sizes[2];
  const int* src = ei;
  const int* dst = ei + E;
  const int M = TT * N;                 // (type, dst) buckets

  char* ws = (char*)d_ws;
  size_t off = 0;
  auto alloc = [&](size_t bytes) {
    void* p = ws + off;
    off += (bytes + 255) & ~(size_t)255;
    return p;
  };
  unsigned short* h    = (unsigned short*)alloc((size_t)N * HD * 2);        // 51.2MB
  unsigned short* accb = (unsigned short*)alloc((size_t)N * HD * 2);        // 51.2MB
  unsigned short* xb   = (unsigned short*)alloc((size_t)N * DD * 2);        // 12.8MB
  unsigned short* WbT  = (unsigned short*)alloc((size_t)TT * HD * DD * 2);  // 0.5MB
  unsigned short* WfT  = (unsigned short*)alloc((size_t)DD * HD * 2);       // 0.13MB
  float* P             = (float*)alloc((size_t)TT * 8 * DD * sizeof(float));
  float* as_           = (float*)alloc((size_t)TT * N * 4 * sizeof(float)); // 3.2MB
  float* ad_           = (float*)alloc((size_t)TT * N * 4 * sizeof(float));
  int* deg             = (int*)alloc((size_t)M * sizeof(int));              // 0.8MB
  int* rowptr          = (int*)alloc((size_t)M * sizeof(int));
  int* cursor          = (int*)alloc((size_t)M * sizeof(int));
  int* slist           = (int*)alloc((size_t)E * sizeof(int));              // 1.3MB
  int* sums            = (int*)alloc(1024 * sizeof(int));

  hipMemsetAsync(deg, 0, (size_t)M * sizeof(int), stream);

  int total4x = N * DD / 4;
  convx_kernel<<<(total4x + 255) / 256, 256, 0, stream>>>(x, xb, total4x);
  prepw_kernel<<<1296, 256, 0, stream>>>(Wg, a_src, a_dst, W_fuse, WbT, P, WfT);
  alpha_all_kernel<<<(N + 3) / 4, 256, 0, stream>>>(x, P, as_, ad_, N);

  // counting sort by (type, dst)
  int nch = (M + 1023) / 1024;          // 196 for N=50000 (must be <= 256)
  hist_kernel<<<(E + 255) / 256, 256, 0, stream>>>(dst, attr, deg, E, N);
  scan1_kernel<<<nch, 1024, 0, stream>>>(deg, rowptr, sums, M);
  scan2_kernel<<<1, 256, 0, stream>>>(sums, nch);
  scan3_kernel<<<nch, 1024, 0, stream>>>(rowptr, sums, cursor, M);
  scatter_kernel<<<(E + 255) / 256, 256, 0, stream>>>(src, dst, attr, cursor, slist, E, N);

  dim3 hgrid((N + 127) / 128, 4);
  for (int t = 0; t < TT; ++t) {
    mfma_h_kernel<<<hgrid, 256, 0, stream>>>(xb, WbT + (size_t)t * HD * DD, h, N);
    msg_gather_kernel<<<(N + 3) / 4, 256, 0, stream>>>(
        slist, rowptr, deg, as_, ad_, h, b_gat, etw, accb, t, N);
  }

  fuse_mfma_kernel<<<(N + 63) / 64, 128, 0, stream>>>(accb, WfT, b_fuse, gamma, beta,
                                                      (float*)d_out, N);
}

// Round 5
// 338.751 us; speedup vs baseline: 4.4362x; 1.4073x over previous
//
#include <hip/hip_runtime.h>
#include <hip/hip_bf16.h>

#define TT 4
#define HH 4
#define DD 128
#define HD 512   // H * D_OUT

typedef __attribute__((ext_vector_type(8))) short short8;
typedef __attribute__((ext_vector_type(4))) float f32x4;

__device__ __forceinline__ float lrelu(float z) { return z > 0.f ? z : 0.2f * z; }
__device__ __forceinline__ float bf2f(unsigned short u) {
  union { unsigned int i; float f; } v; v.i = ((unsigned int)u) << 16; return v.f;
}
__device__ __forceinline__ unsigned short f2b(float f) {
  union { float f; unsigned int i; } u; u.f = f;
  unsigned int r = u.i + 0x7fff + ((u.i >> 16) & 1);
  return (unsigned short)(r >> 16);
}
__device__ __forceinline__ void unpack8(uint4 u, float* hv) {
  hv[0] = bf2f((unsigned short)(u.x & 0xffff));
  hv[1] = bf2f((unsigned short)(u.x >> 16));
  hv[2] = bf2f((unsigned short)(u.y & 0xffff));
  hv[3] = bf2f((unsigned short)(u.y >> 16));
  hv[4] = bf2f((unsigned short)(u.z & 0xffff));
  hv[5] = bf2f((unsigned short)(u.z >> 16));
  hv[6] = bf2f((unsigned short)(u.w & 0xffff));
  hv[7] = bf2f((unsigned short)(u.w >> 16));
}

// -------- x (f32) -> xb (bf16)
__global__ __launch_bounds__(256) void convx_kernel(
    const float* __restrict__ x, unsigned short* __restrict__ xb, int total4) {
  int i = blockIdx.x * 256 + threadIdx.x;
  if (i >= total4) return;
  float4 v = ((const float4*)x)[i];
  ushort4 o;
  o.x = f2b(v.x); o.y = f2b(v.y); o.z = f2b(v.z); o.w = f2b(v.w);
  ((ushort4*)xb)[i] = o;
}

// -------- weights prep: WbT [t][c512][k128] bf16 ; Pb [t][16][128] bf16 ; WfT [c128][k512] bf16
// Pb cols: 0..3 = W@a_s per head, 4..7 = W@a_d per head, 8..15 = zero.
__global__ __launch_bounds__(256) void prepw_kernel(
    const float* __restrict__ Wg, const float* __restrict__ a_s,
    const float* __restrict__ a_d, const float* __restrict__ W_fuse,
    unsigned short* __restrict__ WbT, unsigned short* __restrict__ Pb,
    unsigned short* __restrict__ WfT) {
  int bid = blockIdx.x;
  if (bid < 1024) {                     // WbT: 4*512*128 = 262144 elems
    int idx = bid * 256 + threadIdx.x;
    int k = idx & 127, c = (idx >> 7) & 511, t = idx >> 16;
    WbT[idx] = f2b(Wg[(size_t)t * 65536 + k * 512 + c]);
  } else if (bid < 1056) {              // Pb: 4*16*128 = 8192 elems
    int idx = (bid - 1024) * 256 + threadIdx.x;
    int k = idx & 127, col = (idx >> 7) & 15, t = idx >> 11;
    float s = 0.f;
    if (col < 8) {
      int head = col & 3;
      const float* av = ((col < 4) ? a_s : a_d) + (t * 4 + head) * 128;
      const float* wrow = Wg + (size_t)t * 65536 + k * 512 + head * 128;
      for (int d = 0; d < 128; ++d) s += wrow[d] * av[d];
    }
    Pb[idx] = f2b(s);
  } else {                              // WfT: 128*512 = 65536, bid 1056..1311
    int idx = (bid - 1056) * 256 + threadIdx.x;
    int k = idx & 511, c = idx >> 9;
    WfT[idx] = f2b(W_fuse[(size_t)k * 128 + c]);
  }
}

// -------- counting sort of edges by (type, dst) --------
__global__ __launch_bounds__(256) void hist_kernel(
    const int* __restrict__ dst, const int* __restrict__ attr,
    int* __restrict__ deg, int E, int N) {
  int e = blockIdx.x * 256 + threadIdx.x;
  if (e < E) atomicAdd(&deg[attr[e] * N + dst[e]], 1);
}

__global__ __launch_bounds__(1024) void scan1_kernel(
    const int* __restrict__ deg, int* __restrict__ rowptr,
    int* __restrict__ sums, int M) {
  __shared__ int sh[1024];
  int i = blockIdx.x * 1024 + threadIdx.x;
  int v = (i < M) ? deg[i] : 0;
  sh[threadIdx.x] = v;
  __syncthreads();
  for (int off = 1; off < 1024; off <<= 1) {
    int x = (threadIdx.x >= off) ? sh[threadIdx.x - off] : 0;
    __syncthreads();
    sh[threadIdx.x] += x;
    __syncthreads();
  }
  if (i < M) rowptr[i] = sh[threadIdx.x] - v;   // exclusive within chunk
  if (threadIdx.x == 1023) sums[blockIdx.x] = sh[1023];
}

__global__ __launch_bounds__(256) void scan2_kernel(int* __restrict__ sums, int nch) {
  __shared__ int sh[256];
  int v = (threadIdx.x < nch) ? sums[threadIdx.x] : 0;
  sh[threadIdx.x] = v;
  __syncthreads();
  for (int off = 1; off < 256; off <<= 1) {
    int x = (threadIdx.x >= off) ? sh[threadIdx.x - off] : 0;
    __syncthreads();
    sh[threadIdx.x] += x;
    __syncthreads();
  }
  if (threadIdx.x < nch) sums[threadIdx.x] = sh[threadIdx.x] - v;  // exclusive
}

__global__ __launch_bounds__(1024) void scan3_kernel(
    int* __restrict__ rowptr, const int* __restrict__ sums,
    int* __restrict__ cursor, int M) {
  int i = blockIdx.x * 1024 + threadIdx.x;
  if (i < M) {
    int r = rowptr[i] + sums[blockIdx.x];
    rowptr[i] = r;
    cursor[i] = r;
  }
}

__global__ __launch_bounds__(256) void scatter_kernel(
    const int* __restrict__ src, const int* __restrict__ dst,
    const int* __restrict__ attr, int* __restrict__ cursor,
    int* __restrict__ slist, int E, int N) {
  int e = blockIdx.x * 256 + threadIdx.x;
  if (e >= E) return;
  int p = atomicAdd(&cursor[attr[e] * N + dst[e]], 1);
  slist[p] = src[e];
}

// -------- MFMA GEMM: h[N][512] = xb[N][128] @ W (one type); c0==0 blocks also
// compute alpha_s/alpha_d = xb @ Pb via extra MFMAs (wc==0 waves).
__global__ __launch_bounds__(256) void mfma_h_kernel(
    const unsigned short* __restrict__ xb, const unsigned short* __restrict__ WbT,
    const unsigned short* __restrict__ Pb, unsigned short* __restrict__ h,
    float* __restrict__ as_t, float* __restrict__ ad_t, int N) {
  __shared__ uint4 ldsv[2048];  // 32 KB
  unsigned char* lds = (unsigned char*)ldsv;
  const int n0 = blockIdx.x * 128;
  const int c0 = blockIdx.y * 128;
  const int tid = threadIdx.x;
  const int lane = tid & 63;
  const int wid = tid >> 6;
  const int wr = (wid >> 1) * 64, wc = (wid & 1) * 64;
  const int lr = lane & 15, lg = lane >> 4;

#pragma unroll
  for (int i = 0; i < 8; ++i) {
    int chunk = tid + i * 256;
    int row = chunk >> 4, k16 = chunk & 15;
    int gr = n0 + row;
    uint4 v = make_uint4(0, 0, 0, 0);
    if (gr < N) v = *(const uint4*)(xb + (size_t)gr * DD + k16 * 8);
    *(uint4*)(lds + ((row * 256 + k16 * 16) ^ ((row & 7) << 4))) = v;
  }
  __syncthreads();

  f32x4 acc[4][4] = {};
  f32x4 aacc[4] = {};
  const bool do_alpha = (c0 == 0) && (wc == 0);
#pragma unroll
  for (int kk = 0; kk < 4; ++kk) {
    short8 a[4], b[4];
#pragma unroll
    for (int m = 0; m < 4; ++m) {
      int row = wr + m * 16 + lr;
      a[m] = *(const short8*)(lds + ((row * 256 + kk * 64 + (lg << 4)) ^ ((row & 7) << 4)));
    }
#pragma unroll
    for (int n = 0; n < 4; ++n) {
      int col = c0 + wc + n * 16 + lr;
      b[n] = *(const short8*)(WbT + (size_t)col * DD + kk * 32 + (lg << 3));
    }
#pragma unroll
    for (int m = 0; m < 4; ++m)
#pragma unroll
      for (int n = 0; n < 4; ++n)
        acc[m][n] = __builtin_amdgcn_mfma_f32_16x16x32_bf16(a[m], b[n], acc[m][n], 0, 0, 0);
    if (do_alpha) {
      short8 bp = *(const short8*)(Pb + lr * DD + kk * 32 + (lg << 3));
#pragma unroll
      for (int m = 0; m < 4; ++m)
        aacc[m] = __builtin_amdgcn_mfma_f32_16x16x32_bf16(a[m], bp, aacc[m], 0, 0, 0);
    }
  }
  __syncthreads();

  // alpha write-out (regs only): col=lr (0..7 used), row = wr+m*16+lg*4+r
  if (do_alpha && lr < 8) {
    float* dstp = (lr & 4) ? ad_t : as_t;
    int head = lr & 3;
#pragma unroll
    for (int m = 0; m < 4; ++m)
#pragma unroll
      for (int r = 0; r < 4; ++r) {
        int gr = n0 + wr + m * 16 + lg * 4 + r;
        if (gr < N) dstp[(size_t)gr * 4 + head] = aacc[m][r];
      }
  }

  // bounce C (bf16) through LDS for coalesced store
#pragma unroll
  for (int m = 0; m < 4; ++m)
#pragma unroll
    for (int n = 0; n < 4; ++n) {
      int col = wc + n * 16 + lr;
#pragma unroll
      for (int r = 0; r < 4; ++r) {
        int row = wr + m * 16 + lg * 4 + r;
        *(unsigned short*)(lds + ((row * 256 + col * 2) ^ ((row & 7) << 4))) = f2b(acc[m][n][r]);
      }
    }
  __syncthreads();
#pragma unroll
  for (int i = 0; i < 8; ++i) {
    int chunk = tid + i * 256;
    int row = chunk >> 4, k16 = chunk & 15;
    int gr = n0 + row;
    if (gr < N)
      *(uint4*)(h + (size_t)gr * HD + c0 + k16 * 8) =
          *(const uint4*)(lds + ((row * 256 + k16 * 16) ^ ((row & 7) << 4)));
  }
}

// -------- gather message pass, single-pass unnormalized accumulate.
// Lane layout: head = lane>>4, 8 consecutive d per lane.
__global__ __launch_bounds__(256) void msg_gather_kernel(
    const int* __restrict__ slist, const int* __restrict__ rowptr,
    const int* __restrict__ deg, const float* __restrict__ as_,
    const float* __restrict__ ad_, const unsigned short* __restrict__ h,
    const float* __restrict__ b_gat, const float* __restrict__ etw,
    unsigned short* __restrict__ accb, int t, int N) {
  int d = blockIdx.x * 4 + (threadIdx.x >> 6);
  if (d >= N) return;
  int lane = threadIdx.x & 63;
  int head = lane >> 4;
  int dofs = (lane & 15) * 8;
  size_t tn = (size_t)t * N;

  float adh = ad_[(tn + d) * 4 + head];
  float e = __expf(lrelu(as_[(tn + d) * 4 + head] + adh));
  float den = e;
  float acc8[8], hv[8];
  unpack8(*(const uint4*)(h + (size_t)d * HD + head * DD + dofs), hv);
#pragma unroll
  for (int j = 0; j < 8; ++j) acc8[j] = e * hv[j];

  int base = rowptr[tn + d], dg = deg[tn + d];
  for (int i = 0; i < dg; ++i) {
    int s = slist[base + i];
    e = __expf(lrelu(as_[(tn + s) * 4 + head] + adh));
    den += e;
    unpack8(*(const uint4*)(h + (size_t)s * HD + head * DD + dofs), hv);
#pragma unroll
    for (int j = 0; j < 8; ++j) acc8[j] += e * hv[j];
  }
  float rden = 0.25f / den;
#pragma unroll
  for (int j = 0; j < 8; ++j) {
    acc8[j] *= rden;
    acc8[j] += __shfl_xor(acc8[j], 16);
    acc8[j] += __shfl_xor(acc8[j], 32);
  }
  if (lane < 16) {
    float e0 = etw[0], e1 = etw[1], e2 = etw[2], e3 = etw[3];
    float mx = fmaxf(fmaxf(e0, e1), fmaxf(e2, e3));
    float x0 = __expf(e0 - mx), x1 = __expf(e1 - mx), x2 = __expf(e2 - mx),
          x3 = __expf(e3 - mx);
    float wt = ((t == 0) ? x0 : (t == 1) ? x1 : (t == 2) ? x2 : x3) /
               (x0 + x1 + x2 + x3);
    float4 bg0 = *(const float4*)(b_gat + t * DD + dofs);
    float4 bg1 = *(const float4*)(b_gat + t * DD + dofs + 4);
    unsigned int w0 = (unsigned)f2b(wt * (acc8[0] + bg0.x)) |
                      ((unsigned)f2b(wt * (acc8[1] + bg0.y)) << 16);
    unsigned int w1 = (unsigned)f2b(wt * (acc8[2] + bg0.z)) |
                      ((unsigned)f2b(wt * (acc8[3] + bg0.w)) << 16);
    unsigned int w2 = (unsigned)f2b(wt * (acc8[4] + bg1.x)) |
                      ((unsigned)f2b(wt * (acc8[5] + bg1.y)) << 16);
    unsigned int w3 = (unsigned)f2b(wt * (acc8[6] + bg1.z)) |
                      ((unsigned)f2b(wt * (acc8[7] + bg1.w)) << 16);
    *(uint4*)(accb + (size_t)d * HD + t * DD + dofs) = make_uint4(w0, w1, w2, w3);
  }
}

// -------- MFMA fuse GEMM [N x 512] @ [512 x 128] + LayerNorm + ReLU
__global__ __launch_bounds__(128) void fuse_mfma_kernel(
    const unsigned short* __restrict__ accb, const unsigned short* __restrict__ WfT,
    const float* __restrict__ b_fuse, const float* __restrict__ gamma,
    const float* __restrict__ beta, float* __restrict__ out, int N) {
  __shared__ uint4 ldsv[2048];  // 32 KB (A-stage 16KB, then f32 C-buf 32KB)
  __shared__ float smean[64], srstd[64];
  unsigned char* lds = (unsigned char*)ldsv;
  const int n0 = blockIdx.x * 64;
  const int tid = threadIdx.x;
  const int lane = tid & 63;
  const int wid = tid >> 6;   // 0..1
  const int wc = wid * 64;
  const int lr = lane & 15, lg = lane >> 4;

  f32x4 acc[4][4] = {};
  for (int kt = 0; kt < 4; ++kt) {
#pragma unroll
    for (int i = 0; i < 8; ++i) {
      int chunk = tid + i * 128;        // 0..1023
      int row = chunk >> 4, k16 = chunk & 15;
      int gr = n0 + row;
      uint4 v = make_uint4(0, 0, 0, 0);
      if (gr < N) v = *(const uint4*)(accb + (size_t)gr * HD + kt * 128 + k16 * 8);
      *(uint4*)(lds + ((row * 256 + k16 * 16) ^ ((row & 7) << 4))) = v;
    }
    __syncthreads();
#pragma unroll
    for (int kk = 0; kk < 4; ++kk) {
      short8 a[4], b[4];
#pragma unroll
      for (int m = 0; m < 4; ++m) {
        int row = m * 16 + lr;
        a[m] = *(const short8*)(lds + ((row * 256 + kk * 64 + (lg << 4)) ^ ((row & 7) << 4)));
      }
#pragma unroll
      for (int n = 0; n < 4; ++n) {
        int col = wc + n * 16 + lr;
        b[n] = *(const short8*)(WfT + (size_t)col * HD + kt * 128 + kk * 32 + (lg << 3));
      }
#pragma unroll
      for (int m = 0; m < 4; ++m)
#pragma unroll
        for (int n = 0; n < 4; ++n)
          acc[m][n] = __builtin_amdgcn_mfma_f32_16x16x32_bf16(a[m], b[n], acc[m][n], 0, 0, 0);
    }
    __syncthreads();
  }

#pragma unroll
  for (int m = 0; m < 4; ++m)
#pragma unroll
    for (int n = 0; n < 4; ++n) {
      int col = wc + n * 16 + lr;
      float bf = b_fuse[col];
#pragma unroll
      for (int r = 0; r < 4; ++r) {
        int row = m * 16 + lg * 4 + r;
        *(float*)(lds + ((row * 512 + col * 4) ^ ((row & 7) << 4))) = acc[m][n][r] + bf;
      }
    }
  __syncthreads();

  {
    int row = tid >> 1, half = tid & 1;
    float s = 0.f, ss = 0.f;
#pragma unroll
    for (int j = 0; j < 16; ++j) {
      int byte = (row * 512 + half * 256 + j * 16) ^ ((row & 7) << 4);
      float4 v = *(const float4*)(lds + byte);
      s += v.x + v.y + v.z + v.w;
      ss += v.x * v.x + v.y * v.y + v.z * v.z + v.w * v.w;
    }
    s += __shfl_xor(s, 1);
    ss += __shfl_xor(ss, 1);
    if (half == 0) {
      float mean = s * (1.f / 128.f);
      float var = ss * (1.f / 128.f) - mean * mean;
      smean[row] = mean;
      srstd[row] = rsqrtf(var + 1e-5f);
    }
  }
  __syncthreads();

#pragma unroll
  for (int i = 0; i < 16; ++i) {
    int chunk = tid + i * 128;          // 0..2047
    int row = chunk >> 5, c4 = chunk & 31;
    int gr = n0 + row;
    if (gr < N) {
      int byte = (row * 512 + c4 * 16) ^ ((row & 7) << 4);
      float4 v = *(const float4*)(lds + byte);
      float mean = smean[row], rstd = srstd[row];
      float4 g = *(const float4*)(gamma + c4 * 4);
      float4 bb = *(const float4*)(beta + c4 * 4);
      float4 o;
      o.x = fmaxf(0.f, (v.x - mean) * rstd * g.x + bb.x);
      o.y = fmaxf(0.f, (v.y - mean) * rstd * g.y + bb.y);
      o.z = fmaxf(0.f, (v.z - mean) * rstd * g.z + bb.z);
      o.w = fmaxf(0.f, (v.w - mean) * rstd * g.w + bb.w);
      *(float4*)(out + (size_t)gr * DD + c4 * 4) = o;
    }
  }
}

extern "C" void kernel_launch(void* const* d_in, const int* in_sizes, int n_in,
                              void* d_out, int out_size, void* d_ws, size_t ws_size,
                              hipStream_t stream) {
  const float* x      = (const float*)d_in[0];
  const int*   ei     = (const int*)d_in[1];
  const int*   attr   = (const int*)d_in[2];
  const float* Wg     = (const float*)d_in[3];
  const float* a_src  = (const float*)d_in[4];
  const float* a_dst  = (const float*)d_in[5];
  const float* b_gat  = (const float*)d_in[6];
  const float* etw    = (const float*)d_in[7];
  const float* W_fuse = (const float*)d_in[8];
  const float* b_fuse = (const float*)d_in[9];
  const float* gamma  = (const float*)d_in[10];
  const float* beta   = (const float*)d_in[11];

  const int N = in_sizes[0] / DD;
  const int E = in_sizes[2];
  const int* src = ei;
  const int* dst = ei + E;
  const int M = TT * N;                 // (type, dst) buckets

  char* ws = (char*)d_ws;
  size_t off = 0;
  auto alloc = [&](size_t bytes) {
    void* p = ws + off;
    off += (bytes + 255) & ~(size_t)255;
    return p;
  };
  unsigned short* h    = (unsigned short*)alloc((size_t)N * HD * 2);        // 51.2MB
  unsigned short* accb = (unsigned short*)alloc((size_t)N * HD * 2);        // 51.2MB
  unsigned short* xb   = (unsigned short*)alloc((size_t)N * DD * 2);        // 12.8MB
  unsigned short* WbT  = (unsigned short*)alloc((size_t)TT * HD * DD * 2);  // 0.5MB
  unsigned short* WfT  = (unsigned short*)alloc((size_t)DD * HD * 2);       // 0.13MB
  unsigned short* Pb   = (unsigned short*)alloc((size_t)TT * 16 * DD * 2);  // 16KB
  float* as_           = (float*)alloc((size_t)TT * N * 4 * sizeof(float)); // 3.2MB
  float* ad_           = (float*)alloc((size_t)TT * N * 4 * sizeof(float));
  int* deg             = (int*)alloc((size_t)M * sizeof(int));              // 0.8MB
  int* rowptr          = (int*)alloc((size_t)M * sizeof(int));
  int* cursor          = (int*)alloc((size_t)M * sizeof(int));
  int* slist           = (int*)alloc((size_t)E * sizeof(int));              // 1.3MB
  int* sums            = (int*)alloc(1024 * sizeof(int));

  hipMemsetAsync(deg, 0, (size_t)M * sizeof(int), stream);

  int total4x = N * DD / 4;
  convx_kernel<<<(total4x + 255) / 256, 256, 0, stream>>>(x, xb, total4x);
  prepw_kernel<<<1312, 256, 0, stream>>>(Wg, a_src, a_dst, W_fuse, WbT, Pb, WfT);

  // counting sort by (type, dst)
  int nch = (M + 1023) / 1024;          // 196 for N=50000 (must be <= 256)
  hist_kernel<<<(E + 255) / 256, 256, 0, stream>>>(dst, attr, deg, E, N);
  scan1_kernel<<<nch, 1024, 0, stream>>>(deg, rowptr, sums, M);
  scan2_kernel<<<1, 256, 0, stream>>>(sums, nch);
  scan3_kernel<<<nch, 1024, 0, stream>>>(rowptr, sums, cursor, M);
  scatter_kernel<<<(E + 255) / 256, 256, 0, stream>>>(src, dst, attr, cursor, slist, E, N);

  dim3 hgrid((N + 127) / 128, 4);
  for (int t = 0; t < TT; ++t) {
    mfma_h_kernel<<<hgrid, 256, 0, stream>>>(
        xb, WbT + (size_t)t * HD * DD, Pb + (size_t)t * 16 * DD, h,
        as_ + (size_t)t * N * 4, ad_ + (size_t)t * N * 4, N);
    msg_gather_kernel<<<(N + 3) / 4, 256, 0, stream>>>(
        slist, rowptr, deg, as_, ad_, h, b_gat, etw, accb, t, N);
  }

  fuse_mfma_kernel<<<(N + 63) / 64, 128, 0, stream>>>(accb, WfT, b_fuse, gamma, beta,
                                                      (float*)d_out, N);
}

// Round 6
// 311.335 us; speedup vs baseline: 4.8269x; 1.0881x over previous
//
#include <hip/hip_runtime.h>
#include <hip/hip_bf16.h>

#define TT 4
#define HH 4
#define DD 128
#define KAGG 2048   // TT * HH * DD

typedef __attribute__((ext_vector_type(8))) short short8;
typedef __attribute__((ext_vector_type(4))) float f32x4;

__device__ __forceinline__ float lrelu(float z) { return z > 0.f ? z : 0.2f * z; }
__device__ __forceinline__ float bf2f(unsigned short u) {
  union { unsigned int i; float f; } v; v.i = ((unsigned int)u) << 16; return v.f;
}
__device__ __forceinline__ unsigned short f2b(float f) {
  union { float f; unsigned int i; } u; u.f = f;
  unsigned int r = u.i + 0x7fff + ((u.i >> 16) & 1);
  return (unsigned short)(r >> 16);
}
__device__ __forceinline__ void unpack8(uint4 u, float* hv) {
  hv[0] = bf2f((unsigned short)(u.x & 0xffff));
  hv[1] = bf2f((unsigned short)(u.x >> 16));
  hv[2] = bf2f((unsigned short)(u.y & 0xffff));
  hv[3] = bf2f((unsigned short)(u.y >> 16));
  hv[4] = bf2f((unsigned short)(u.z & 0xffff));
  hv[5] = bf2f((unsigned short)(u.z >> 16));
  hv[6] = bf2f((unsigned short)(u.w & 0xffff));
  hv[7] = bf2f((unsigned short)(u.w >> 16));
}

// -------- x (f32) -> xb (bf16)
__global__ __launch_bounds__(256) void convx_kernel(
    const float* __restrict__ x, unsigned short* __restrict__ xb, int total4) {
  int i = blockIdx.x * 256 + threadIdx.x;
  if (i >= total4) return;
  float4 v = ((const float4*)x)[i];
  ushort4 o;
  o.x = f2b(v.x); o.y = f2b(v.y); o.z = f2b(v.z); o.w = f2b(v.w);
  ((ushort4*)xb)[i] = o;
}

// -------- prep: G_T [j=128][K=2048] bf16 (collapsed W_gat@W_fuse, scaled);
//          Pall [c=32][k=128] bf16 (alpha projectors); cbias [128] f32.
// K = t*512 + head*128 + k ;  c = t*8 + j, j<4 -> a_src head j, j>=4 -> a_dst.
__global__ __launch_bounds__(256) void prepw_kernel(
    const float* __restrict__ Wg, const float* __restrict__ a_s,
    const float* __restrict__ a_d, const float* __restrict__ W_fuse,
    const float* __restrict__ b_gat, const float* __restrict__ etw,
    const float* __restrict__ b_fuse, unsigned short* __restrict__ G_T,
    unsigned short* __restrict__ Pall, float* __restrict__ cbias) {
  float e0 = etw[0], e1 = etw[1], e2 = etw[2], e3 = etw[3];
  float mx = fmaxf(fmaxf(e0, e1), fmaxf(e2, e3));
  float w0 = __expf(e0 - mx), w1 = __expf(e1 - mx), w2 = __expf(e2 - mx),
        w3 = __expf(e3 - mx);
  float inv = 1.f / (w0 + w1 + w2 + w3);
  float wts[4] = {w0 * inv, w1 * inv, w2 * inv, w3 * inv};

  int bid = blockIdx.x;
  if (bid < 1024) {                       // G_T: 128*2048 elems, idx = j*2048+K
    int idx = bid * 256 + threadIdx.x;
    int j = idx >> 11, K = idx & 2047;
    int t = K >> 9, head = (K >> 7) & 3, k = K & 127;
    const float* wr = Wg + (size_t)t * 65536 + k * 512 + head * 128;
    const float* wf = W_fuse + (size_t)t * 128 * 128 + j;
    float s = 0.f;
    for (int m = 0; m < 128; ++m) s += wr[m] * wf[(size_t)m * 128];
    G_T[idx] = f2b(0.25f * wts[t] * s);
  } else if (bid < 1040) {                // Pall: 32*128 = 4096
    int idx = (bid - 1024) * 256 + threadIdx.x;
    int c = idx >> 7, k = idx & 127;
    int t = c >> 3, jj = c & 7, head = jj & 3;
    const float* av = ((jj < 4) ? a_s : a_d) + (t * 4 + head) * 128;
    const float* wr = Wg + (size_t)t * 65536 + k * 512 + head * 128;
    float s = 0.f;
    for (int m = 0; m < 128; ++m) s += wr[m] * av[m];
    Pall[c * 128 + k] = f2b(s);
  } else {                                // cbias
    int j = threadIdx.x;
    if (j < 128) {
      float s = b_fuse[j];
      for (int t = 0; t < 4; ++t) {
        float st = 0.f;
        for (int m = 0; m < 128; ++m)
          st += b_gat[t * 128 + m] * W_fuse[(size_t)(t * 128 + m) * 128 + j];
        s += wts[t] * st;
      }
      cbias[j] = s;
    }
  }
}

// -------- alpha via MFMA: [as|ad][t][n][head] = xb @ Pall
__global__ __launch_bounds__(256) void alpha_mfma_kernel(
    const unsigned short* __restrict__ xb, const unsigned short* __restrict__ Pall,
    float* __restrict__ as_, float* __restrict__ ad_, int N) {
  __shared__ uint4 ldsv[2048];  // 32KB
  unsigned char* lds = (unsigned char*)ldsv;
  const int n0 = blockIdx.x * 128;
  const int tid = threadIdx.x, lane = tid & 63, wid = tid >> 6;
  const int lr = lane & 15, lg = lane >> 4;
#pragma unroll
  for (int i = 0; i < 8; ++i) {
    int chunk = tid + i * 256;
    int row = chunk >> 4, k16 = chunk & 15;
    int gr = n0 + row;
    uint4 v = make_uint4(0, 0, 0, 0);
    if (gr < N) v = *(const uint4*)(xb + (size_t)gr * DD + k16 * 8);
    *(uint4*)(lds + ((row * 256 + k16 * 16) ^ ((row & 7) << 4))) = v;
  }
  __syncthreads();
  f32x4 acc[2][2] = {};
#pragma unroll
  for (int kk = 0; kk < 4; ++kk) {
    short8 a[2], b[2];
#pragma unroll
    for (int m = 0; m < 2; ++m) {
      int row = wid * 32 + m * 16 + lr;
      a[m] = *(const short8*)(lds + ((row * 256 + kk * 64 + (lg << 4)) ^ ((row & 7) << 4)));
    }
#pragma unroll
    for (int n = 0; n < 2; ++n) {
      int c = n * 16 + lr;
      b[n] = *(const short8*)(Pall + c * DD + kk * 32 + lg * 8);
    }
#pragma unroll
    for (int m = 0; m < 2; ++m)
#pragma unroll
      for (int n = 0; n < 2; ++n)
        acc[m][n] = __builtin_amdgcn_mfma_f32_16x16x32_bf16(a[m], b[n], acc[m][n], 0, 0, 0);
  }
#pragma unroll
  for (int m = 0; m < 2; ++m)
#pragma unroll
    for (int n = 0; n < 2; ++n) {
      int c = n * 16 + lr;
      int t = c >> 3, jj = c & 7, head = jj & 3;
      float* dstp = (jj & 4) ? ad_ : as_;
#pragma unroll
      for (int r = 0; r < 4; ++r) {
        int gr = n0 + wid * 32 + m * 16 + lg * 4 + r;
        if (gr < N) dstp[((size_t)t * N + gr) * 4 + head] = acc[m][n][r];
      }
    }
}

// -------- counting sort of edges by (type, dst) --------
__global__ __launch_bounds__(256) void hist_kernel(
    const int* __restrict__ dst, const int* __restrict__ attr,
    int* __restrict__ deg, int E, int N) {
  int e = blockIdx.x * 256 + threadIdx.x;
  if (e < E) atomicAdd(&deg[attr[e] * N + dst[e]], 1);
}

__global__ __launch_bounds__(1024) void scan1_kernel(
    const int* __restrict__ deg, int* __restrict__ rowptr,
    int* __restrict__ sums, int M) {
  __shared__ int sh[1024];
  int i = blockIdx.x * 1024 + threadIdx.x;
  int v = (i < M) ? deg[i] : 0;
  sh[threadIdx.x] = v;
  __syncthreads();
  for (int off = 1; off < 1024; off <<= 1) {
    int x = (threadIdx.x >= off) ? sh[threadIdx.x - off] : 0;
    __syncthreads();
    sh[threadIdx.x] += x;
    __syncthreads();
  }
  if (i < M) rowptr[i] = sh[threadIdx.x] - v;
  if (threadIdx.x == 1023) sums[blockIdx.x] = sh[1023];
}

__global__ __launch_bounds__(256) void scan2_kernel(int* __restrict__ sums, int nch) {
  __shared__ int sh[256];
  int v = (threadIdx.x < nch) ? sums[threadIdx.x] : 0;
  sh[threadIdx.x] = v;
  __syncthreads();
  for (int off = 1; off < 256; off <<= 1) {
    int x = (threadIdx.x >= off) ? sh[threadIdx.x - off] : 0;
    __syncthreads();
    sh[threadIdx.x] += x;
    __syncthreads();
  }
  if (threadIdx.x < nch) sums[threadIdx.x] = sh[threadIdx.x] - v;
}

__global__ __launch_bounds__(1024) void scan3_kernel(
    int* __restrict__ rowptr, const int* __restrict__ sums,
    int* __restrict__ cursor, int M) {
  int i = blockIdx.x * 1024 + threadIdx.x;
  if (i < M) {
    int r = rowptr[i] + sums[blockIdx.x];
    rowptr[i] = r;
    cursor[i] = r;
  }
}

__global__ __launch_bounds__(256) void scatter_kernel(
    const int* __restrict__ src, const int* __restrict__ dst,
    const int* __restrict__ attr, int* __restrict__ cursor,
    int* __restrict__ slist, int E, int N) {
  int e = blockIdx.x * 256 + threadIdx.x;
  if (e >= E) return;
  int p = atomicAdd(&cursor[attr[e] * N + dst[e]], 1);
  slist[p] = src[e];
}

// -------- gather in x-space: one wave per (t, dst); AGG[d][t*512+head*128+dofs]
__global__ __launch_bounds__(256) void gather_kernel(
    const int* __restrict__ slist, const int* __restrict__ rowptr,
    const int* __restrict__ deg, const float* __restrict__ as_,
    const float* __restrict__ ad_, const unsigned short* __restrict__ xb,
    unsigned short* __restrict__ AGG, int N) {
  int t = blockIdx.y;
  int d = blockIdx.x * 4 + (threadIdx.x >> 6);
  if (d >= N) return;
  int lane = threadIdx.x & 63;
  int head = lane >> 4;
  int dofs = (lane & 15) * 8;
  size_t tn = (size_t)t * N;

  float adh = ad_[(tn + d) * 4 + head];
  float es = __expf(lrelu(as_[(tn + d) * 4 + head] + adh));
  float den = es;
  float acc8[8], hv[8];
  unpack8(*(const uint4*)(xb + (size_t)d * DD + dofs), hv);
#pragma unroll
  for (int j = 0; j < 8; ++j) acc8[j] = es * hv[j];

  int base = rowptr[tn + d], dg = deg[tn + d];
  int i = 0;
  for (; i + 1 < dg; i += 2) {
    int s0 = slist[base + i], s1 = slist[base + i + 1];
    float av0 = as_[(tn + s0) * 4 + head];
    float av1 = as_[(tn + s1) * 4 + head];
    uint4 u0 = *(const uint4*)(xb + (size_t)s0 * DD + dofs);
    uint4 u1 = *(const uint4*)(xb + (size_t)s1 * DD + dofs);
    float q0 = __expf(lrelu(av0 + adh));
    float q1 = __expf(lrelu(av1 + adh));
    den += q0 + q1;
    unpack8(u0, hv);
#pragma unroll
    for (int j = 0; j < 8; ++j) acc8[j] += q0 * hv[j];
    unpack8(u1, hv);
#pragma unroll
    for (int j = 0; j < 8; ++j) acc8[j] += q1 * hv[j];
  }
  if (i < dg) {
    int s = slist[base + i];
    float av = as_[(tn + s) * 4 + head];
    uint4 u = *(const uint4*)(xb + (size_t)s * DD + dofs);
    float q = __expf(lrelu(av + adh));
    den += q;
    unpack8(u, hv);
#pragma unroll
    for (int j = 0; j < 8; ++j) acc8[j] += q * hv[j];
  }

  float r = 1.f / den;
  unsigned int p0 = (unsigned)f2b(acc8[0] * r) | ((unsigned)f2b(acc8[1] * r) << 16);
  unsigned int p1 = (unsigned)f2b(acc8[2] * r) | ((unsigned)f2b(acc8[3] * r) << 16);
  unsigned int p2 = (unsigned)f2b(acc8[4] * r) | ((unsigned)f2b(acc8[5] * r) << 16);
  unsigned int p3 = (unsigned)f2b(acc8[6] * r) | ((unsigned)f2b(acc8[7] * r) << 16);
  *(uint4*)(AGG + (size_t)d * KAGG + t * 512 + lane * 8) = make_uint4(p0, p1, p2, p3);
}

// -------- final GEMM [N,2048]@[2048,128] + cbias + LayerNorm + ReLU
// 4 waves/block, 128 rows; wave owns 32 rows x 128 cols -> LN fully in-wave.
__global__ __launch_bounds__(256) void gemmln_kernel(
    const unsigned short* __restrict__ AGG, const unsigned short* __restrict__ G_T,
    const float* __restrict__ cbias, const float* __restrict__ gamma,
    const float* __restrict__ beta, float* __restrict__ out, int N) {
  __shared__ uint4 ldsv[2048];  // 32KB A-stage
  unsigned char* lds = (unsigned char*)ldsv;
  const int n0 = blockIdx.x * 128;
  const int tid = threadIdx.x, lane = tid & 63, wid = tid >> 6;
  const int lr = lane & 15, lg = lane >> 4;

  f32x4 acc[2][8] = {};
  for (int kt = 0; kt < 16; ++kt) {
#pragma unroll
    for (int i = 0; i < 8; ++i) {
      int chunk = tid + i * 256;
      int row = chunk >> 4, k16 = chunk & 15;
      int gr = n0 + row;
      uint4 v = make_uint4(0, 0, 0, 0);
      if (gr < N) v = *(const uint4*)(AGG + (size_t)gr * KAGG + kt * 128 + k16 * 8);
      *(uint4*)(lds + ((row * 256 + k16 * 16) ^ ((row & 7) << 4))) = v;
    }
    __syncthreads();
#pragma unroll
    for (int kk = 0; kk < 4; ++kk) {
      short8 a[2], b[8];
#pragma unroll
      for (int m = 0; m < 2; ++m) {
        int row = wid * 32 + m * 16 + lr;
        a[m] = *(const short8*)(lds + ((row * 256 + kk * 64 + (lg << 4)) ^ ((row & 7) << 4)));
      }
#pragma unroll
      for (int n = 0; n < 8; ++n) {
        int col = n * 16 + lr;
        b[n] = *(const short8*)(G_T + (size_t)col * KAGG + kt * 128 + kk * 32 + lg * 8);
      }
#pragma unroll
      for (int m = 0; m < 2; ++m)
#pragma unroll
        for (int n = 0; n < 8; ++n)
          acc[m][n] = __builtin_amdgcn_mfma_f32_16x16x32_bf16(a[m], b[n], acc[m][n], 0, 0, 0);
    }
    __syncthreads();
  }

  float cb[8], gm[8], bt[8];
#pragma unroll
  for (int n = 0; n < 8; ++n) {
    cb[n] = cbias[n * 16 + lr];
    gm[n] = gamma[n * 16 + lr];
    bt[n] = beta[n * 16 + lr];
  }
#pragma unroll
  for (int m = 0; m < 2; ++m)
#pragma unroll
    for (int r = 0; r < 4; ++r) {
      float y[8];
      float s = 0.f, ss = 0.f;
#pragma unroll
      for (int n = 0; n < 8; ++n) {
        y[n] = acc[m][n][r] + cb[n];
        s += y[n];
        ss += y[n] * y[n];
      }
#pragma unroll
      for (int mask = 1; mask <= 8; mask <<= 1) {
        s += __shfl_xor(s, mask);
        ss += __shfl_xor(ss, mask);
      }
      float mean = s * (1.f / 128.f);
      float var = ss * (1.f / 128.f) - mean * mean;
      float rstd = rsqrtf(var + 1e-5f);
      int gr = n0 + wid * 32 + m * 16 + lg * 4 + r;
      if (gr < N) {
#pragma unroll
        for (int n = 0; n < 8; ++n) {
          float v = (y[n] - mean) * rstd * gm[n] + bt[n];
          out[(size_t)gr * DD + n * 16 + lr] = fmaxf(0.f, v);
        }
      }
    }
}

extern "C" void kernel_launch(void* const* d_in, const int* in_sizes, int n_in,
                              void* d_out, int out_size, void* d_ws, size_t ws_size,
                              hipStream_t stream) {
  const float* x      = (const float*)d_in[0];
  const int*   ei     = (const int*)d_in[1];
  const int*   attr   = (const int*)d_in[2];
  const float* Wg     = (const float*)d_in[3];
  const float* a_src  = (const float*)d_in[4];
  const float* a_dst  = (const float*)d_in[5];
  const float* b_gat  = (const float*)d_in[6];
  const float* etw    = (const float*)d_in[7];
  const float* W_fuse = (const float*)d_in[8];
  const float* b_fuse = (const float*)d_in[9];
  const float* gamma  = (const float*)d_in[10];
  const float* beta   = (const float*)d_in[11];

  const int N = in_sizes[0] / DD;
  const int E = in_sizes[2];
  const int* src = ei;
  const int* dst = ei + E;
  const int M = TT * N;

  char* ws = (char*)d_ws;
  size_t off = 0;
  auto alloc = [&](size_t bytes) {
    void* p = ws + off;
    off += (bytes + 255) & ~(size_t)255;
    return p;
  };
  unsigned short* AGG  = (unsigned short*)alloc((size_t)N * KAGG * 2);      // 204.8MB
  unsigned short* xb   = (unsigned short*)alloc((size_t)N * DD * 2);        // 12.8MB
  unsigned short* G_T  = (unsigned short*)alloc((size_t)DD * KAGG * 2);     // 512KB
  unsigned short* Pall = (unsigned short*)alloc((size_t)32 * DD * 2);       // 8KB
  float* cbias         = (float*)alloc(128 * sizeof(float));
  float* as_           = (float*)alloc((size_t)TT * N * 4 * sizeof(float)); // 3.2MB
  float* ad_           = (float*)alloc((size_t)TT * N * 4 * sizeof(float));
  int* deg             = (int*)alloc((size_t)M * sizeof(int));              // 0.8MB
  int* rowptr          = (int*)alloc((size_t)M * sizeof(int));
  int* cursor          = (int*)alloc((size_t)M * sizeof(int));
  int* slist           = (int*)alloc((size_t)E * sizeof(int));              // 1.3MB
  int* sums            = (int*)alloc(1024 * sizeof(int));

  hipMemsetAsync(deg, 0, (size_t)M * sizeof(int), stream);

  int total4x = N * DD / 4;
  convx_kernel<<<(total4x + 255) / 256, 256, 0, stream>>>(x, xb, total4x);
  prepw_kernel<<<1041, 256, 0, stream>>>(Wg, a_src, a_dst, W_fuse, b_gat, etw,
                                         b_fuse, G_T, Pall, cbias);
  hist_kernel<<<(E + 255) / 256, 256, 0, stream>>>(dst, attr, deg, E, N);
  int nch = (M + 1023) / 1024;
  scan1_kernel<<<nch, 1024, 0, stream>>>(deg, rowptr, sums, M);
  scan2_kernel<<<1, 256, 0, stream>>>(sums, nch);
  scan3_kernel<<<nch, 1024, 0, stream>>>(rowptr, sums, cursor, M);
  scatter_kernel<<<(E + 255) / 256, 256, 0, stream>>>(src, dst, attr, cursor, slist, E, N);

  alpha_mfma_kernel<<<(N + 127) / 128, 256, 0, stream>>>(xb, Pall, as_, ad_, N);

  dim3 ggrid((N + 3) / 4, TT);
  gather_kernel<<<ggrid, 256, 0, stream>>>(slist, rowptr, deg, as_, ad_, xb, AGG, N);

  gemmln_kernel<<<(N + 127) / 128, 256, 0, stream>>>(AGG, G_T, cbias, gamma, beta,
                                                     (float*)d_out, N);
}

// Round 7
// 300.663 us; speedup vs baseline: 4.9982x; 1.0355x over previous
//
#include <hip/hip_runtime.h>
#include <hip/hip_bf16.h>

#define TT 4
#define HH 4
#define DD 128
#define KAGG 2048   // TT * HH * DD

typedef __attribute__((ext_vector_type(8))) short short8;
typedef __attribute__((ext_vector_type(4))) float f32x4;

__device__ __forceinline__ float lrelu(float z) { return z > 0.f ? z : 0.2f * z; }
__device__ __forceinline__ float bf2f(unsigned short u) {
  union { unsigned int i; float f; } v; v.i = ((unsigned int)u) << 16; return v.f;
}
__device__ __forceinline__ unsigned short f2b(float f) {
  union { float f; unsigned int i; } u; u.f = f;
  unsigned int r = u.i + 0x7fff + ((u.i >> 16) & 1);
  return (unsigned short)(r >> 16);
}
__device__ __forceinline__ void unpack8(uint4 u, float* hv) {
  hv[0] = bf2f((unsigned short)(u.x & 0xffff));
  hv[1] = bf2f((unsigned short)(u.x >> 16));
  hv[2] = bf2f((unsigned short)(u.y & 0xffff));
  hv[3] = bf2f((unsigned short)(u.y >> 16));
  hv[4] = bf2f((unsigned short)(u.z & 0xffff));
  hv[5] = bf2f((unsigned short)(u.z >> 16));
  hv[6] = bf2f((unsigned short)(u.w & 0xffff));
  hv[7] = bf2f((unsigned short)(u.w >> 16));
}

// -------- x (f32) -> xb (bf16)
__global__ __launch_bounds__(256) void convx_kernel(
    const float* __restrict__ x, unsigned short* __restrict__ xb, int total4) {
  int i = blockIdx.x * 256 + threadIdx.x;
  if (i >= total4) return;
  float4 v = ((const float4*)x)[i];
  ushort4 o;
  o.x = f2b(v.x); o.y = f2b(v.y); o.z = f2b(v.z); o.w = f2b(v.w);
  ((ushort4*)xb)[i] = o;
}

// -------- prep: Gfrag (collapsed W_gat@W_fuse, scaled, in MFMA fragment order);
//          Pall [c=32][k=128] bf16 (alpha projectors); cbias [128] f32.
// Gfrag fragment f = (kt*4+kk)*8+n holds B[k=kt*128+kk*32+lg*8+j][col=n*16+lr]
// at Gfrag[f*512 + lane*8 + j]  -> one coalesced 1KB load per wave.
__global__ __launch_bounds__(256) void prepw_kernel(
    const float* __restrict__ Wg, const float* __restrict__ a_s,
    const float* __restrict__ a_d, const float* __restrict__ W_fuse,
    const float* __restrict__ b_gat, const float* __restrict__ etw,
    const float* __restrict__ b_fuse, unsigned short* __restrict__ Gfrag,
    unsigned short* __restrict__ Pall, float* __restrict__ cbias) {
  float e0 = etw[0], e1 = etw[1], e2 = etw[2], e3 = etw[3];
  float mx = fmaxf(fmaxf(e0, e1), fmaxf(e2, e3));
  float w0 = __expf(e0 - mx), w1 = __expf(e1 - mx), w2 = __expf(e2 - mx),
        w3 = __expf(e3 - mx);
  float inv = 1.f / (w0 + w1 + w2 + w3);
  float wts[4] = {w0 * inv, w1 * inv, w2 * inv, w3 * inv};

  int bid = blockIdx.x;
  if (bid < 1024) {                       // Gfrag: 512 frags * 512 shorts
    int idx = bid * 256 + threadIdx.x;
    int f = idx >> 9, l = (idx >> 3) & 63, j = idx & 7;
    int kt = f >> 5, kk = (f >> 3) & 3, n = f & 7;
    int K = kt * 128 + kk * 32 + (l >> 4) * 8 + j;
    int col = n * 16 + (l & 15);
    int t = K >> 9, head = (K >> 7) & 3, k = K & 127;
    const float* wr = Wg + (size_t)t * 65536 + k * 512 + head * 128;
    const float* wf = W_fuse + (size_t)t * 128 * 128 + col;
    float s = 0.f;
    for (int m = 0; m < 128; ++m) s += wr[m] * wf[(size_t)m * 128];
    Gfrag[idx] = f2b(0.25f * wts[t] * s);
  } else if (bid < 1040) {                // Pall: 32*128 = 4096
    int idx = (bid - 1024) * 256 + threadIdx.x;
    int c = idx >> 7, k = idx & 127;
    int t = c >> 3, jj = c & 7, head = jj & 3;
    const float* av = ((jj < 4) ? a_s : a_d) + (t * 4 + head) * 128;
    const float* wr = Wg + (size_t)t * 65536 + k * 512 + head * 128;
    float s = 0.f;
    for (int m = 0; m < 128; ++m) s += wr[m] * av[m];
    Pall[c * 128 + k] = f2b(s);
  } else {                                // cbias
    int j = threadIdx.x;
    if (j < 128) {
      float s = b_fuse[j];
      for (int t = 0; t < 4; ++t) {
        float st = 0.f;
        for (int m = 0; m < 128; ++m)
          st += b_gat[t * 128 + m] * W_fuse[(size_t)(t * 128 + m) * 128 + j];
        s += wts[t] * st;
      }
      cbias[j] = s;
    }
  }
}

// -------- alpha via MFMA: [as|ad][t][n][head] = xb @ Pall
__global__ __launch_bounds__(256) void alpha_mfma_kernel(
    const unsigned short* __restrict__ xb, const unsigned short* __restrict__ Pall,
    float* __restrict__ as_, float* __restrict__ ad_, int N) {
  __shared__ uint4 ldsv[2048];  // 32KB
  unsigned char* lds = (unsigned char*)ldsv;
  const int n0 = blockIdx.x * 128;
  const int tid = threadIdx.x, lane = tid & 63, wid = tid >> 6;
  const int lr = lane & 15, lg = lane >> 4;
#pragma unroll
  for (int i = 0; i < 8; ++i) {
    int chunk = tid + i * 256;
    int row = chunk >> 4, k16 = chunk & 15;
    int gr = n0 + row;
    uint4 v = make_uint4(0, 0, 0, 0);
    if (gr < N) v = *(const uint4*)(xb + (size_t)gr * DD + k16 * 8);
    *(uint4*)(lds + ((row * 256 + k16 * 16) ^ ((row & 7) << 4))) = v;
  }
  __syncthreads();
  f32x4 acc[2][2] = {};
#pragma unroll
  for (int kk = 0; kk < 4; ++kk) {
    short8 a[2], b[2];
#pragma unroll
    for (int m = 0; m < 2; ++m) {
      int row = wid * 32 + m * 16 + lr;
      a[m] = *(const short8*)(lds + ((row * 256 + kk * 64 + (lg << 4)) ^ ((row & 7) << 4)));
    }
#pragma unroll
    for (int n = 0; n < 2; ++n) {
      int c = n * 16 + lr;
      b[n] = *(const short8*)(Pall + c * DD + kk * 32 + lg * 8);
    }
#pragma unroll
    for (int m = 0; m < 2; ++m)
#pragma unroll
      for (int n = 0; n < 2; ++n)
        acc[m][n] = __builtin_amdgcn_mfma_f32_16x16x32_bf16(a[m], b[n], acc[m][n], 0, 0, 0);
  }
#pragma unroll
  for (int m = 0; m < 2; ++m)
#pragma unroll
    for (int n = 0; n < 2; ++n) {
      int c = n * 16 + lr;
      int t = c >> 3, jj = c & 7, head = jj & 3;
      float* dstp = (jj & 4) ? ad_ : as_;
#pragma unroll
      for (int r = 0; r < 4; ++r) {
        int gr = n0 + wid * 32 + m * 16 + lg * 4 + r;
        if (gr < N) dstp[((size_t)t * N + gr) * 4 + head] = acc[m][n][r];
      }
    }
}

// -------- counting sort of edges by (type, dst) --------
__global__ __launch_bounds__(256) void hist_kernel(
    const int* __restrict__ dst, const int* __restrict__ attr,
    int* __restrict__ deg, int E, int N) {
  int e = blockIdx.x * 256 + threadIdx.x;
  if (e < E) atomicAdd(&deg[attr[e] * N + dst[e]], 1);
}

__global__ __launch_bounds__(1024) void scan1_kernel(
    const int* __restrict__ deg, int* __restrict__ rowptr,
    int* __restrict__ sums, int M) {
  __shared__ int sh[1024];
  int i = blockIdx.x * 1024 + threadIdx.x;
  int v = (i < M) ? deg[i] : 0;
  sh[threadIdx.x] = v;
  __syncthreads();
  for (int off = 1; off < 1024; off <<= 1) {
    int x = (threadIdx.x >= off) ? sh[threadIdx.x - off] : 0;
    __syncthreads();
    sh[threadIdx.x] += x;
    __syncthreads();
  }
  if (i < M) rowptr[i] = sh[threadIdx.x] - v;
  if (threadIdx.x == 1023) sums[blockIdx.x] = sh[1023];
}

__global__ __launch_bounds__(256) void scan2_kernel(int* __restrict__ sums, int nch) {
  __shared__ int sh[256];
  int v = (threadIdx.x < nch) ? sums[threadIdx.x] : 0;
  sh[threadIdx.x] = v;
  __syncthreads();
  for (int off = 1; off < 256; off <<= 1) {
    int x = (threadIdx.x >= off) ? sh[threadIdx.x - off] : 0;
    __syncthreads();
    sh[threadIdx.x] += x;
    __syncthreads();
  }
  if (threadIdx.x < nch) sums[threadIdx.x] = sh[threadIdx.x] - v;
}

__global__ __launch_bounds__(1024) void scan3_kernel(
    int* __restrict__ rowptr, const int* __restrict__ sums,
    int* __restrict__ cursor, int M) {
  int i = blockIdx.x * 1024 + threadIdx.x;
  if (i < M) {
    int r = rowptr[i] + sums[blockIdx.x];
    rowptr[i] = r;
    cursor[i] = r;
  }
}

__global__ __launch_bounds__(256) void scatter_kernel(
    const int* __restrict__ src, const int* __restrict__ dst,
    const int* __restrict__ attr, int* __restrict__ cursor,
    int* __restrict__ slist, int E, int N) {
  int e = blockIdx.x * 256 + threadIdx.x;
  if (e >= E) return;
  int p = atomicAdd(&cursor[attr[e] * N + dst[e]], 1);
  slist[p] = src[e];
}

// -------- gather in x-space: one wave per (t, dst); AGG[d][t*512+head*128+dofs]
__global__ __launch_bounds__(256) void gather_kernel(
    const int* __restrict__ slist, const int* __restrict__ rowptr,
    const int* __restrict__ deg, const float* __restrict__ as_,
    const float* __restrict__ ad_, const unsigned short* __restrict__ xb,
    unsigned short* __restrict__ AGG, int N) {
  int t = blockIdx.y;
  int d = blockIdx.x * 4 + (threadIdx.x >> 6);
  if (d >= N) return;
  int lane = threadIdx.x & 63;
  int head = lane >> 4;
  int dofs = (lane & 15) * 8;
  size_t tn = (size_t)t * N;

  float adh = ad_[(tn + d) * 4 + head];
  float es = __expf(lrelu(as_[(tn + d) * 4 + head] + adh));
  float den = es;
  float acc8[8], hv[8];
  unpack8(*(const uint4*)(xb + (size_t)d * DD + dofs), hv);
#pragma unroll
  for (int j = 0; j < 8; ++j) acc8[j] = es * hv[j];

  int base = rowptr[tn + d], dg = deg[tn + d];
  int i = 0;
  for (; i + 1 < dg; i += 2) {
    int s0 = slist[base + i], s1 = slist[base + i + 1];
    float av0 = as_[(tn + s0) * 4 + head];
    float av1 = as_[(tn + s1) * 4 + head];
    uint4 u0 = *(const uint4*)(xb + (size_t)s0 * DD + dofs);
    uint4 u1 = *(const uint4*)(xb + (size_t)s1 * DD + dofs);
    float q0 = __expf(lrelu(av0 + adh));
    float q1 = __expf(lrelu(av1 + adh));
    den += q0 + q1;
    unpack8(u0, hv);
#pragma unroll
    for (int j = 0; j < 8; ++j) acc8[j] += q0 * hv[j];
    unpack8(u1, hv);
#pragma unroll
    for (int j = 0; j < 8; ++j) acc8[j] += q1 * hv[j];
  }
  if (i < dg) {
    int s = slist[base + i];
    float av = as_[(tn + s) * 4 + head];
    uint4 u = *(const uint4*)(xb + (size_t)s * DD + dofs);
    float q = __expf(lrelu(av + adh));
    den += q;
    unpack8(u, hv);
#pragma unroll
    for (int j = 0; j < 8; ++j) acc8[j] += q * hv[j];
  }

  float r = 1.f / den;
  unsigned int p0 = (unsigned)f2b(acc8[0] * r) | ((unsigned)f2b(acc8[1] * r) << 16);
  unsigned int p1 = (unsigned)f2b(acc8[2] * r) | ((unsigned)f2b(acc8[3] * r) << 16);
  unsigned int p2 = (unsigned)f2b(acc8[4] * r) | ((unsigned)f2b(acc8[5] * r) << 16);
  unsigned int p3 = (unsigned)f2b(acc8[6] * r) | ((unsigned)f2b(acc8[7] * r) << 16);
  *(uint4*)(AGG + (size_t)d * KAGG + t * 512 + lane * 8) = make_uint4(p0, p1, p2, p3);
}

// -------- final GEMM [N,2048]@[2048,128] + cbias + LayerNorm + ReLU
// 64 rows/block, 4 waves (16 rows each); B from Gfrag (coalesced, L2-resident);
// next-kt A prefetched to regs while current kt computes (T14 split).
__global__ __launch_bounds__(256) void gemmln_kernel(
    const unsigned short* __restrict__ AGG, const unsigned short* __restrict__ Gfrag,
    const float* __restrict__ cbias, const float* __restrict__ gamma,
    const float* __restrict__ beta, float* __restrict__ out, int N) {
  __shared__ uint4 ldsv[1024];  // 16KB: 64 rows x 128 k bf16, swizzled
  unsigned char* lds = (unsigned char*)ldsv;
  const int n0 = blockIdx.x * 64;
  const int tid = threadIdx.x, lane = tid & 63, wid = tid >> 6;
  const int lr = lane & 15, lg = lane >> 4;
  const int srow = tid >> 4, sk16 = tid & 15;   // staging: 4 rows-groups of 16 chunks

  uint4 r[4];
#pragma unroll
  for (int i = 0; i < 4; ++i) {
    int row = srow + i * 16;
    int gr = n0 + row;
    r[i] = make_uint4(0, 0, 0, 0);
    if (gr < N) r[i] = *(const uint4*)(AGG + (size_t)gr * KAGG + sk16 * 8);
  }

  f32x4 acc[8] = {};
  for (int kt = 0; kt < 16; ++kt) {
#pragma unroll
    for (int i = 0; i < 4; ++i) {
      int row = srow + i * 16;
      *(uint4*)(lds + ((row * 256 + sk16 * 16) ^ ((row & 7) << 4))) = r[i];
    }
    __syncthreads();
    if (kt < 15) {
#pragma unroll
      for (int i = 0; i < 4; ++i) {
        int row = srow + i * 16;
        int gr = n0 + row;
        r[i] = make_uint4(0, 0, 0, 0);
        if (gr < N)
          r[i] = *(const uint4*)(AGG + (size_t)gr * KAGG + (kt + 1) * 128 + sk16 * 8);
      }
    }
#pragma unroll
    for (int kk = 0; kk < 4; ++kk) {
      int row = wid * 16 + lr;
      short8 a = *(const short8*)(lds + ((row * 256 + kk * 64 + (lg << 4)) ^ ((row & 7) << 4)));
      const unsigned short* gf = Gfrag + (((size_t)(kt * 4 + kk) * 8) << 9) + lane * 8;
#pragma unroll
      for (int n = 0; n < 8; ++n) {
        short8 b = *(const short8*)(gf + ((size_t)n << 9));
        acc[n] = __builtin_amdgcn_mfma_f32_16x16x32_bf16(a, b, acc[n], 0, 0, 0);
      }
    }
    __syncthreads();
  }

  float cb[8], gm[8], bt[8];
#pragma unroll
  for (int n = 0; n < 8; ++n) {
    cb[n] = cbias[n * 16 + lr];
    gm[n] = gamma[n * 16 + lr];
    bt[n] = beta[n * 16 + lr];
  }
#pragma unroll
  for (int rr = 0; rr < 4; ++rr) {
    float y[8];
    float s = 0.f, ss = 0.f;
#pragma unroll
    for (int n = 0; n < 8; ++n) {
      y[n] = acc[n][rr] + cb[n];
      s += y[n];
      ss += y[n] * y[n];
    }
#pragma unroll
    for (int mask = 1; mask <= 8; mask <<= 1) {
      s += __shfl_xor(s, mask);
      ss += __shfl_xor(ss, mask);
    }
    float mean = s * (1.f / 128.f);
    float var = ss * (1.f / 128.f) - mean * mean;
    float rstd = rsqrtf(var + 1e-5f);
    int gr = n0 + wid * 16 + lg * 4 + rr;
    if (gr < N) {
#pragma unroll
      for (int n = 0; n < 8; ++n) {
        float v = (y[n] - mean) * rstd * gm[n] + bt[n];
        out[(size_t)gr * DD + n * 16 + lr] = fmaxf(0.f, v);
      }
    }
  }
}

extern "C" void kernel_launch(void* const* d_in, const int* in_sizes, int n_in,
                              void* d_out, int out_size, void* d_ws, size_t ws_size,
                              hipStream_t stream) {
  const float* x      = (const float*)d_in[0];
  const int*   ei     = (const int*)d_in[1];
  const int*   attr   = (const int*)d_in[2];
  const float* Wg     = (const float*)d_in[3];
  const float* a_src  = (const float*)d_in[4];
  const float* a_dst  = (const float*)d_in[5];
  const float* b_gat  = (const float*)d_in[6];
  const float* etw    = (const float*)d_in[7];
  const float* W_fuse = (const float*)d_in[8];
  const float* b_fuse = (const float*)d_in[9];
  const float* gamma  = (const float*)d_in[10];
  const float* beta   = (const float*)d_in[11];

  const int N = in_sizes[0] / DD;
  const int E = in_sizes[2];
  const int* src = ei;
  const int* dst = ei + E;
  const int M = TT * N;

  char* ws = (char*)d_ws;
  size_t off = 0;
  auto alloc = [&](size_t bytes) {
    void* p = ws + off;
    off += (bytes + 255) & ~(size_t)255;
    return p;
  };
  unsigned short* AGG   = (unsigned short*)alloc((size_t)N * KAGG * 2);      // 204.8MB
  unsigned short* xb    = (unsigned short*)alloc((size_t)N * DD * 2);        // 12.8MB
  unsigned short* Gfrag = (unsigned short*)alloc((size_t)512 * 512 * 2);     // 512KB
  unsigned short* Pall  = (unsigned short*)alloc((size_t)32 * DD * 2);       // 8KB
  float* cbias          = (float*)alloc(128 * sizeof(float));
  float* as_            = (float*)alloc((size_t)TT * N * 4 * sizeof(float)); // 3.2MB
  float* ad_            = (float*)alloc((size_t)TT * N * 4 * sizeof(float));
  int* deg              = (int*)alloc((size_t)M * sizeof(int));              // 0.8MB
  int* rowptr           = (int*)alloc((size_t)M * sizeof(int));
  int* cursor           = (int*)alloc((size_t)M * sizeof(int));
  int* slist            = (int*)alloc((size_t)E * sizeof(int));              // 1.3MB
  int* sums             = (int*)alloc(1024 * sizeof(int));

  hipMemsetAsync(deg, 0, (size_t)M * sizeof(int), stream);

  int total4x = N * DD / 4;
  convx_kernel<<<(total4x + 255) / 256, 256, 0, stream>>>(x, xb, total4x);
  prepw_kernel<<<1041, 256, 0, stream>>>(Wg, a_src, a_dst, W_fuse, b_gat, etw,
                                         b_fuse, Gfrag, Pall, cbias);
  hist_kernel<<<(E + 255) / 256, 256, 0, stream>>>(dst, attr, deg, E, N);
  int nch = (M + 1023) / 1024;
  scan1_kernel<<<nch, 1024, 0, stream>>>(deg, rowptr, sums, M);
  scan2_kernel<<<1, 256, 0, stream>>>(sums, nch);
  scan3_kernel<<<nch, 1024, 0, stream>>>(rowptr, sums, cursor, M);
  scatter_kernel<<<(E + 255) / 256, 256, 0, stream>>>(src, dst, attr, cursor, slist, E, N);

  alpha_mfma_kernel<<<(N + 127) / 128, 256, 0, stream>>>(xb, Pall, as_, ad_, N);

  dim3 ggrid((N + 3) / 4, TT);
  gather_kernel<<<ggrid, 256, 0, stream>>>(slist, rowptr, deg, as_, ad_, xb, AGG, N);

  gemmln_kernel<<<(N + 63) / 64, 256, 0, stream>>>(AGG, Gfrag, cbias, gamma, beta,
                                                   (float*)d_out, N);
}

// Round 8
// 209.944 us; speedup vs baseline: 7.1580x; 1.4321x over previous
//
#include <hip/hip_runtime.h>
#include <hip/hip_bf16.h>

#define TT 4
#define HH 4
#define DD 128
#define KAGG 2048   // TT * HH * DD

typedef __attribute__((ext_vector_type(8))) short short8;
typedef __attribute__((ext_vector_type(4))) float f32x4;

__device__ __forceinline__ float lrelu(float z) { return z > 0.f ? z : 0.2f * z; }
__device__ __forceinline__ float bf2f(unsigned short u) {
  union { unsigned int i; float f; } v; v.i = ((unsigned int)u) << 16; return v.f;
}
__device__ __forceinline__ unsigned short f2b(float f) {
  union { float f; unsigned int i; } u; u.f = f;
  unsigned int r = u.i + 0x7fff + ((u.i >> 16) & 1);
  return (unsigned short)(r >> 16);
}
__device__ __forceinline__ void unpack8(uint4 u, float* hv) {
  hv[0] = bf2f((unsigned short)(u.x & 0xffff));
  hv[1] = bf2f((unsigned short)(u.x >> 16));
  hv[2] = bf2f((unsigned short)(u.y & 0xffff));
  hv[3] = bf2f((unsigned short)(u.y >> 16));
  hv[4] = bf2f((unsigned short)(u.z & 0xffff));
  hv[5] = bf2f((unsigned short)(u.z >> 16));
  hv[6] = bf2f((unsigned short)(u.w & 0xffff));
  hv[7] = bf2f((unsigned short)(u.w >> 16));
}

// -------- x (f32) -> xb (bf16)
__global__ __launch_bounds__(256) void convx_kernel(
    const float* __restrict__ x, unsigned short* __restrict__ xb, int total4) {
  int i = blockIdx.x * 256 + threadIdx.x;
  if (i >= total4) return;
  float4 v = ((const float4*)x)[i];
  ushort4 o;
  o.x = f2b(v.x); o.y = f2b(v.y); o.z = f2b(v.z); o.w = f2b(v.w);
  ((ushort4*)xb)[i] = o;
}

// -------- prep: Gfrag (collapsed W_gat@W_fuse, scaled, in MFMA fragment order);
//          Pall [c=32][k=128] bf16 (alpha projectors); cbias [128] f32.
// Gfrag fragment f = (kt*4+kk)*8+n holds B[k=kt*128+kk*32+lg*8+j][col=n*16+lr]
// at Gfrag[f*512 + lane*8 + j].
__global__ __launch_bounds__(256) void prepw_kernel(
    const float* __restrict__ Wg, const float* __restrict__ a_s,
    const float* __restrict__ a_d, const float* __restrict__ W_fuse,
    const float* __restrict__ b_gat, const float* __restrict__ etw,
    const float* __restrict__ b_fuse, unsigned short* __restrict__ Gfrag,
    unsigned short* __restrict__ Pall, float* __restrict__ cbias) {
  float e0 = etw[0], e1 = etw[1], e2 = etw[2], e3 = etw[3];
  float mx = fmaxf(fmaxf(e0, e1), fmaxf(e2, e3));
  float w0 = __expf(e0 - mx), w1 = __expf(e1 - mx), w2 = __expf(e2 - mx),
        w3 = __expf(e3 - mx);
  float inv = 1.f / (w0 + w1 + w2 + w3);
  float wts[4] = {w0 * inv, w1 * inv, w2 * inv, w3 * inv};

  int bid = blockIdx.x;
  if (bid < 1024) {                       // Gfrag: 512 frags * 512 shorts
    int idx = bid * 256 + threadIdx.x;
    int f = idx >> 9, l = (idx >> 3) & 63, j = idx & 7;
    int kt = f >> 5, kk = (f >> 3) & 3, n = f & 7;
    int K = kt * 128 + kk * 32 + (l >> 4) * 8 + j;
    int col = n * 16 + (l & 15);
    int t = K >> 9, head = (K >> 7) & 3, k = K & 127;
    const float* wr = Wg + (size_t)t * 65536 + k * 512 + head * 128;
    const float* wf = W_fuse + (size_t)t * 128 * 128 + col;
    float s = 0.f;
    for (int m = 0; m < 128; ++m) s += wr[m] * wf[(size_t)m * 128];
    Gfrag[idx] = f2b(0.25f * wts[t] * s);
  } else if (bid < 1040) {                // Pall: 32*128 = 4096
    int idx = (bid - 1024) * 256 + threadIdx.x;
    int c = idx >> 7, k = idx & 127;
    int t = c >> 3, jj = c & 7, head = jj & 3;
    const float* av = ((jj < 4) ? a_s : a_d) + (t * 4 + head) * 128;
    const float* wr = Wg + (size_t)t * 65536 + k * 512 + head * 128;
    float s = 0.f;
    for (int m = 0; m < 128; ++m) s += wr[m] * av[m];
    Pall[c * 128 + k] = f2b(s);
  } else {                                // cbias
    int j = threadIdx.x;
    if (j < 128) {
      float s = b_fuse[j];
      for (int t = 0; t < 4; ++t) {
        float st = 0.f;
        for (int m = 0; m < 128; ++m)
          st += b_gat[t * 128 + m] * W_fuse[(size_t)(t * 128 + m) * 128 + j];
        s += wts[t] * st;
      }
      cbias[j] = s;
    }
  }
}

// -------- alpha via MFMA: [as|ad][t][n][head] = xb @ Pall
__global__ __launch_bounds__(256) void alpha_mfma_kernel(
    const unsigned short* __restrict__ xb, const unsigned short* __restrict__ Pall,
    float* __restrict__ as_, float* __restrict__ ad_, int N) {
  __shared__ uint4 ldsv[2048];  // 32KB
  unsigned char* lds = (unsigned char*)ldsv;
  const int n0 = blockIdx.x * 128;
  const int tid = threadIdx.x, lane = tid & 63, wid = tid >> 6;
  const int lr = lane & 15, lg = lane >> 4;
#pragma unroll
  for (int i = 0; i < 8; ++i) {
    int chunk = tid + i * 256;
    int row = chunk >> 4, k16 = chunk & 15;
    int gr = n0 + row;
    uint4 v = make_uint4(0, 0, 0, 0);
    if (gr < N) v = *(const uint4*)(xb + (size_t)gr * DD + k16 * 8);
    *(uint4*)(lds + ((row * 256 + k16 * 16) ^ ((row & 7) << 4))) = v;
  }
  __syncthreads();
  f32x4 acc[2][2] = {};
#pragma unroll
  for (int kk = 0; kk < 4; ++kk) {
    short8 a[2], b[2];
#pragma unroll
    for (int m = 0; m < 2; ++m) {
      int row = wid * 32 + m * 16 + lr;
      a[m] = *(const short8*)(lds + ((row * 256 + kk * 64 + (lg << 4)) ^ ((row & 7) << 4)));
    }
#pragma unroll
    for (int n = 0; n < 2; ++n) {
      int c = n * 16 + lr;
      b[n] = *(const short8*)(Pall + c * DD + kk * 32 + lg * 8);
    }
#pragma unroll
    for (int m = 0; m < 2; ++m)
#pragma unroll
      for (int n = 0; n < 2; ++n)
        acc[m][n] = __builtin_amdgcn_mfma_f32_16x16x32_bf16(a[m], b[n], acc[m][n], 0, 0, 0);
  }
#pragma unroll
  for (int m = 0; m < 2; ++m)
#pragma unroll
    for (int n = 0; n < 2; ++n) {
      int c = n * 16 + lr;
      int t = c >> 3, jj = c & 7, head = jj & 3;
      float* dstp = (jj & 4) ? ad_ : as_;
#pragma unroll
      for (int r = 0; r < 4; ++r) {
        int gr = n0 + wid * 32 + m * 16 + lg * 4 + r;
        if (gr < N) dstp[((size_t)t * N + gr) * 4 + head] = acc[m][n][r];
      }
    }
}

// -------- counting sort of edges by (type, dst) --------
__global__ __launch_bounds__(256) void hist_kernel(
    const int* __restrict__ dst, const int* __restrict__ attr,
    int* __restrict__ deg, int E, int N) {
  int e = blockIdx.x * 256 + threadIdx.x;
  if (e < E) atomicAdd(&deg[attr[e] * N + dst[e]], 1);
}

__global__ __launch_bounds__(1024) void scan1_kernel(
    const int* __restrict__ deg, int* __restrict__ rowptr,
    int* __restrict__ sums, int M) {
  __shared__ int sh[1024];
  int i = blockIdx.x * 1024 + threadIdx.x;
  int v = (i < M) ? deg[i] : 0;
  sh[threadIdx.x] = v;
  __syncthreads();
  for (int off = 1; off < 1024; off <<= 1) {
    int x = (threadIdx.x >= off) ? sh[threadIdx.x - off] : 0;
    __syncthreads();
    sh[threadIdx.x] += x;
    __syncthreads();
  }
  if (i < M) rowptr[i] = sh[threadIdx.x] - v;
  if (threadIdx.x == 1023) sums[blockIdx.x] = sh[1023];
}

__global__ __launch_bounds__(256) void scan2_kernel(int* __restrict__ sums, int nch) {
  __shared__ int sh[256];
  int v = (threadIdx.x < nch) ? sums[threadIdx.x] : 0;
  sh[threadIdx.x] = v;
  __syncthreads();
  for (int off = 1; off < 256; off <<= 1) {
    int x = (threadIdx.x >= off) ? sh[threadIdx.x - off] : 0;
    __syncthreads();
    sh[threadIdx.x] += x;
    __syncthreads();
  }
  if (threadIdx.x < nch) sums[threadIdx.x] = sh[threadIdx.x] - v;
}

__global__ __launch_bounds__(1024) void scan3_kernel(
    int* __restrict__ rowptr, const int* __restrict__ sums,
    int* __restrict__ cursor, int M) {
  int i = blockIdx.x * 1024 + threadIdx.x;
  if (i < M) {
    int r = rowptr[i] + sums[blockIdx.x];
    rowptr[i] = r;
    cursor[i] = r;
  }
}

__global__ __launch_bounds__(256) void scatter_kernel(
    const int* __restrict__ src, const int* __restrict__ dst,
    const int* __restrict__ attr, int* __restrict__ cursor,
    int* __restrict__ slist, int E, int N) {
  int e = blockIdx.x * 256 + threadIdx.x;
  if (e >= E) return;
  int p = atomicAdd(&cursor[attr[e] * N + dst[e]], 1);
  slist[p] = src[e];
}

// -------- gather in x-space: one wave per (t, dst); AGG[d][t*512+head*128+dofs]
__global__ __launch_bounds__(256) void gather_kernel(
    const int* __restrict__ slist, const int* __restrict__ rowptr,
    const int* __restrict__ deg, const float* __restrict__ as_,
    const float* __restrict__ ad_, const unsigned short* __restrict__ xb,
    unsigned short* __restrict__ AGG, int N) {
  int t = blockIdx.y;
  int d = blockIdx.x * 4 + (threadIdx.x >> 6);
  if (d >= N) return;
  int lane = threadIdx.x & 63;
  int head = lane >> 4;
  int dofs = (lane & 15) * 8;
  size_t tn = (size_t)t * N;

  float adh = ad_[(tn + d) * 4 + head];
  float es = __expf(lrelu(as_[(tn + d) * 4 + head] + adh));
  float den = es;
  float acc8[8], hv[8];
  unpack8(*(const uint4*)(xb + (size_t)d * DD + dofs), hv);
#pragma unroll
  for (int j = 0; j < 8; ++j) acc8[j] = es * hv[j];

  int base = rowptr[tn + d], dg = deg[tn + d];
  int i = 0;
  for (; i + 1 < dg; i += 2) {
    int s0 = slist[base + i], s1 = slist[base + i + 1];
    float av0 = as_[(tn + s0) * 4 + head];
    float av1 = as_[(tn + s1) * 4 + head];
    uint4 u0 = *(const uint4*)(xb + (size_t)s0 * DD + dofs);
    uint4 u1 = *(const uint4*)(xb + (size_t)s1 * DD + dofs);
    float q0 = __expf(lrelu(av0 + adh));
    float q1 = __expf(lrelu(av1 + adh));
    den += q0 + q1;
    unpack8(u0, hv);
#pragma unroll
    for (int j = 0; j < 8; ++j) acc8[j] += q0 * hv[j];
    unpack8(u1, hv);
#pragma unroll
    for (int j = 0; j < 8; ++j) acc8[j] += q1 * hv[j];
  }
  if (i < dg) {
    int s = slist[base + i];
    float av = as_[(tn + s) * 4 + head];
    uint4 u = *(const uint4*)(xb + (size_t)s * DD + dofs);
    float q = __expf(lrelu(av + adh));
    den += q;
    unpack8(u, hv);
#pragma unroll
    for (int j = 0; j < 8; ++j) acc8[j] += q * hv[j];
  }

  float r = 1.f / den;
  unsigned int p0 = (unsigned)f2b(acc8[0] * r) | ((unsigned)f2b(acc8[1] * r) << 16);
  unsigned int p1 = (unsigned)f2b(acc8[2] * r) | ((unsigned)f2b(acc8[3] * r) << 16);
  unsigned int p2 = (unsigned)f2b(acc8[4] * r) | ((unsigned)f2b(acc8[5] * r) << 16);
  unsigned int p3 = (unsigned)f2b(acc8[6] * r) | ((unsigned)f2b(acc8[7] * r) << 16);
  *(uint4*)(AGG + (size_t)d * KAGG + t * 512 + lane * 8) = make_uint4(p0, p1, p2, p3);
}

// -------- final GEMM [N,2048]@[2048,128] + cbias + LayerNorm + ReLU
// 128 rows/block, 4 waves (32 rows each). B(kt) staged in double-buffered LDS
// (linear copy of Gfrag fragment block); A reg-prefetched one kt ahead (T14).
__global__ __launch_bounds__(256) void gemmln_kernel(
    const unsigned short* __restrict__ AGG, const unsigned short* __restrict__ Gfrag,
    const float* __restrict__ cbias, const float* __restrict__ gamma,
    const float* __restrict__ beta, float* __restrict__ out, int N) {
  __shared__ uint4 bbuf[2][2048];   // 2 x 32KB B tiles
  const int n0 = blockIdx.x * 128;
  const int tid = threadIdx.x, lane = tid & 63, wid = tid >> 6;
  const int lr = lane & 15, lg = lane >> 4;
  const int wrow = n0 + wid * 32;

  uint4 bn[8], an[8], ac[8];
  // load B(0), A(0)
#pragma unroll
  for (int i = 0; i < 8; ++i)
    bn[i] = *(const uint4*)(Gfrag + (size_t)(i * 256 + tid) * 8);
#pragma unroll
  for (int i = 0; i < 8; ++i) {
    int m = i >> 2, kk = i & 3;
    int gr = wrow + m * 16 + lr;
    an[i] = make_uint4(0, 0, 0, 0);
    if (gr < N) an[i] = *(const uint4*)(AGG + (size_t)gr * KAGG + kk * 32 + lg * 8);
  }
#pragma unroll
  for (int i = 0; i < 8; ++i) bbuf[0][i * 256 + tid] = bn[i];
  __syncthreads();
#pragma unroll
  for (int i = 0; i < 8; ++i) ac[i] = an[i];

  f32x4 acc[2][8] = {};
  int cur = 0;
  for (int kt = 0; kt < 16; ++kt) {
    if (kt < 15) {
#pragma unroll
      for (int i = 0; i < 8; ++i)
        bn[i] = *(const uint4*)(Gfrag + (size_t)(kt + 1) * 16384 + (size_t)(i * 256 + tid) * 8);
#pragma unroll
      for (int i = 0; i < 8; ++i) {
        int m = i >> 2, kk = i & 3;
        int gr = wrow + m * 16 + lr;
        an[i] = make_uint4(0, 0, 0, 0);
        if (gr < N)
          an[i] = *(const uint4*)(AGG + (size_t)gr * KAGG + (kt + 1) * 128 + kk * 32 + lg * 8);
      }
    }
    const unsigned char* lds = (const unsigned char*)bbuf[cur];
#pragma unroll
    for (int kk = 0; kk < 4; ++kk) {
      short8 a0 = *(const short8*)&ac[0 * 4 + kk];
      short8 a1 = *(const short8*)&ac[1 * 4 + kk];
#pragma unroll
      for (int n = 0; n < 8; ++n) {
        short8 b = *(const short8*)(lds + (kk * 8 + n) * 1024 + lane * 16);
        acc[0][n] = __builtin_amdgcn_mfma_f32_16x16x32_bf16(a0, b, acc[0][n], 0, 0, 0);
        acc[1][n] = __builtin_amdgcn_mfma_f32_16x16x32_bf16(a1, b, acc[1][n], 0, 0, 0);
      }
    }
    if (kt < 15) {
#pragma unroll
      for (int i = 0; i < 8; ++i) bbuf[cur ^ 1][i * 256 + tid] = bn[i];
      __syncthreads();
      cur ^= 1;
#pragma unroll
      for (int i = 0; i < 8; ++i) ac[i] = an[i];
    }
  }

  float cb[8], gm[8], bt[8];
#pragma unroll
  for (int n = 0; n < 8; ++n) {
    cb[n] = cbias[n * 16 + lr];
    gm[n] = gamma[n * 16 + lr];
    bt[n] = beta[n * 16 + lr];
  }
#pragma unroll
  for (int m = 0; m < 2; ++m)
#pragma unroll
    for (int rr = 0; rr < 4; ++rr) {
      float y[8];
      float s = 0.f, ss = 0.f;
#pragma unroll
      for (int n = 0; n < 8; ++n) {
        y[n] = acc[m][n][rr] + cb[n];
        s += y[n];
        ss += y[n] * y[n];
      }
#pragma unroll
      for (int mask = 1; mask <= 8; mask <<= 1) {
        s += __shfl_xor(s, mask);
        ss += __shfl_xor(ss, mask);
      }
      float mean = s * (1.f / 128.f);
      float var = ss * (1.f / 128.f) - mean * mean;
      float rstd = rsqrtf(var + 1e-5f);
      int gr = wrow + m * 16 + lg * 4 + rr;
      if (gr < N) {
#pragma unroll
        for (int n = 0; n < 8; ++n) {
          float v = (y[n] - mean) * rstd * gm[n] + bt[n];
          out[(size_t)gr * DD + n * 16 + lr] = fmaxf(0.f, v);
        }
      }
    }
}

extern "C" void kernel_launch(void* const* d_in, const int* in_sizes, int n_in,
                              void* d_out, int out_size, void* d_ws, size_t ws_size,
                              hipStream_t stream) {
  const float* x      = (const float*)d_in[0];
  const int*   ei     = (const int*)d_in[1];
  const int*   attr   = (const int*)d_in[2];
  const float* Wg     = (const float*)d_in[3];
  const float* a_src  = (const float*)d_in[4];
  const float* a_dst  = (const float*)d_in[5];
  const float* b_gat  = (const float*)d_in[6];
  const float* etw    = (const float*)d_in[7];
  const float* W_fuse = (const float*)d_in[8];
  const float* b_fuse = (const float*)d_in[9];
  const float* gamma  = (const float*)d_in[10];
  const float* beta   = (const float*)d_in[11];

  const int N = in_sizes[0] / DD;
  const int E = in_sizes[2];
  const int* src = ei;
  const int* dst = ei + E;
  const int M = TT * N;

  char* ws = (char*)d_ws;
  size_t off = 0;
  auto alloc = [&](size_t bytes) {
    void* p = ws + off;
    off += (bytes + 255) & ~(size_t)255;
    return p;
  };
  unsigned short* AGG   = (unsigned short*)alloc((size_t)N * KAGG * 2);      // 204.8MB
  unsigned short* xb    = (unsigned short*)alloc((size_t)N * DD * 2);        // 12.8MB
  unsigned short* Gfrag = (unsigned short*)alloc((size_t)512 * 512 * 2);     // 512KB
  unsigned short* Pall  = (unsigned short*)alloc((size_t)32 * DD * 2);       // 8KB
  float* cbias          = (float*)alloc(128 * sizeof(float));
  float* as_            = (float*)alloc((size_t)TT * N * 4 * sizeof(float)); // 3.2MB
  float* ad_            = (float*)alloc((size_t)TT * N * 4 * sizeof(float));
  int* deg              = (int*)alloc((size_t)M * sizeof(int));              // 0.8MB
  int* rowptr           = (int*)alloc((size_t)M * sizeof(int));
  int* cursor           = (int*)alloc((size_t)M * sizeof(int));
  int* slist            = (int*)alloc((size_t)E * sizeof(int));              // 1.3MB
  int* sums             = (int*)alloc(1024 * sizeof(int));

  hipMemsetAsync(deg, 0, (size_t)M * sizeof(int), stream);

  int total4x = N * DD / 4;
  convx_kernel<<<(total4x + 255) / 256, 256, 0, stream>>>(x, xb, total4x);
  prepw_kernel<<<1041, 256, 0, stream>>>(Wg, a_src, a_dst, W_fuse, b_gat, etw,
                                         b_fuse, Gfrag, Pall, cbias);
  hist_kernel<<<(E + 255) / 256, 256, 0, stream>>>(dst, attr, deg, E, N);
  int nch = (M + 1023) / 1024;
  scan1_kernel<<<nch, 1024, 0, stream>>>(deg, rowptr, sums, M);
  scan2_kernel<<<1, 256, 0, stream>>>(sums, nch);
  scan3_kernel<<<nch, 1024, 0, stream>>>(rowptr, sums, cursor, M);
  scatter_kernel<<<(E + 255) / 256, 256, 0, stream>>>(src, dst, attr, cursor, slist, E, N);

  alpha_mfma_kernel<<<(N + 127) / 128, 256, 0, stream>>>(xb, Pall, as_, ad_, N);

  dim3 ggrid((N + 3) / 4, TT);
  gather_kernel<<<ggrid, 256, 0, stream>>>(slist, rowptr, deg, as_, ad_, xb, AGG, N);

  gemmln_kernel<<<(N + 127) / 128, 256, 0, stream>>>(AGG, Gfrag, cbias, gamma, beta,
                                                     (float*)d_out, N);
}